// Round 1
// baseline (5599.046 us; speedup 1.0000x reference)
//
#include <hip/hip_runtime.h>
#include <math.h>

static constexpr int N = 4096;           // B*L
static constexpr int D = 1024;
static constexpr int V = 32000;
static constexpr int K = 8;
static constexpr int S = 20;             // vocab slices
static constexpr int CPS = V / S;        // 1600 cols per slice
static constexpr int TR = 64;            // rows per block
static constexpr int TC = 64;            // cols per tile
static constexpr int DK = 64;            // k-chunk
static constexpr int LST = 68;           // LDS stride in words (16B-aligned rows, breaks bank degeneracy)
static constexpr int NCT = CPS / TC;     // 25 col-tiles per slice

// ---------------------------------------------------------------- zero probs
__global__ void zero_kernel(float4* __restrict__ p, int n4) {
  int i = blockIdx.x * blockDim.x + threadIdx.x;
  int stride = gridDim.x * blockDim.x;
  float4 z = make_float4(0.f, 0.f, 0.f, 0.f);
  for (; i < n4; i += stride) p[i] = z;
}

// ------------------------------------------------------- inverse row L2 norm
__global__ void rownorm_kernel(const float* __restrict__ x, float* __restrict__ inv) {
  int row = blockIdx.x;
  const float4* xr = reinterpret_cast<const float4*>(x + (size_t)row * D);
  float4 v = xr[threadIdx.x];                      // 256 thr * 4 = 1024 elems
  float ss = v.x * v.x + v.y * v.y + v.z * v.z + v.w * v.w;
#pragma unroll
  for (int off = 32; off > 0; off >>= 1) ss += __shfl_down(ss, off, 64);
  __shared__ float wsum[4];
  if ((threadIdx.x & 63) == 0) wsum[threadIdx.x >> 6] = ss;
  __syncthreads();
  if (threadIdx.x == 0) {
    float t = wsum[0] + wsum[1] + wsum[2] + wsum[3];
    inv[row] = 1.0f / fmaxf(sqrtf(t), 1e-12f);     // matches x / max(norm, eps)
  }
}

// --------------------------------------- fused sims GEMM + per-slice top-8
// grid: (S, N/TR). block 256 = 16x16 threads, 4x4 micro-tile -> 64x64 sim tile.
__global__ __launch_bounds__(256, 4)
void simtopk_kernel(const float* __restrict__ emb, const float* __restrict__ vocab,
                    const float* __restrict__ invq, const float* __restrict__ invv,
                    float* __restrict__ cand_val, int* __restrict__ cand_idx) {
  __shared__ __align__(16) float lds[2 * DK * LST];   // QT | VT, reused as simtile
  __shared__ float tval[TR][K];
  __shared__ int   tidx[TR][K];
  __shared__ float invq_s[TR];

  const int tid = threadIdx.x;
  const int slice = blockIdx.x;
  const int rbase = blockIdx.y * TR;
  const int ty = tid >> 4, tx = tid & 15;
  const int lrow = tid >> 4;     // staging row group 0..15
  const int lc4  = tid & 15;     // staging float4-col 0..15

  if (tid < TR) {
    invq_s[tid] = invq[rbase + tid];
#pragma unroll
    for (int j = 0; j < K; ++j) { tval[tid][j] = -3.0e38f; tidx[tid][j] = 0; }
  }
  __syncthreads();

  float* qlds = lds;
  float* vlds = lds + DK * LST;

  for (int ct = 0; ct < NCT; ++ct) {
    const int cbase = slice * CPS + ct * TC;
    float acc[4][4] = {};
    float4 qreg[4], vreg[4];

    // prefetch dk=0 tile into registers (global only, no LDS touch)
#pragma unroll
    for (int f = 0; f < 4; ++f) {
      int r = lrow + 16 * f;
      qreg[f] = *reinterpret_cast<const float4*>(&emb[(size_t)(rbase + r) * D + lc4 * 4]);
      vreg[f] = *reinterpret_cast<const float4*>(&vocab[(size_t)(cbase + r) * D + lc4 * 4]);
    }

    for (int dk = 0; dk < D / DK; ++dk) {
      __syncthreads();                               // LDS free (prev compute / scan done)
      // regs -> LDS, transposed [d][row], q scaled by its inv-norm
#pragma unroll
      for (int f = 0; f < 4; ++f) {
        int r = lrow + 16 * f;
        float qs = invq_s[r];
        float4 q = qreg[f];
        int c0 = lc4 * 4;
        qlds[(c0 + 0) * LST + r] = q.x * qs;
        qlds[(c0 + 1) * LST + r] = q.y * qs;
        qlds[(c0 + 2) * LST + r] = q.z * qs;
        qlds[(c0 + 3) * LST + r] = q.w * qs;
        float4 vv = vreg[f];
        vlds[(c0 + 0) * LST + r] = vv.x;
        vlds[(c0 + 1) * LST + r] = vv.y;
        vlds[(c0 + 2) * LST + r] = vv.z;
        vlds[(c0 + 3) * LST + r] = vv.w;
      }
      __syncthreads();
      // issue next tile's global loads early; HBM latency hides under compute
      if (dk + 1 < D / DK) {
        const int dbase = (dk + 1) * DK;
#pragma unroll
        for (int f = 0; f < 4; ++f) {
          int r = lrow + 16 * f;
          qreg[f] = *reinterpret_cast<const float4*>(&emb[(size_t)(rbase + r) * D + dbase + lc4 * 4]);
          vreg[f] = *reinterpret_cast<const float4*>(&vocab[(size_t)(cbase + r) * D + dbase + lc4 * 4]);
        }
      }
      // outer-product micro-kernel: per d, 2x ds_read_b128 + 16 FMA
#pragma unroll 16
      for (int d = 0; d < DK; ++d) {
        float4 qa = *reinterpret_cast<const float4*>(&qlds[d * LST + ty * 4]);
        float4 vb = *reinterpret_cast<const float4*>(&vlds[d * LST + tx * 4]);
        acc[0][0] += qa.x * vb.x; acc[0][1] += qa.x * vb.y; acc[0][2] += qa.x * vb.z; acc[0][3] += qa.x * vb.w;
        acc[1][0] += qa.y * vb.x; acc[1][1] += qa.y * vb.y; acc[1][2] += qa.y * vb.z; acc[1][3] += qa.y * vb.w;
        acc[2][0] += qa.z * vb.x; acc[2][1] += qa.z * vb.y; acc[2][2] += qa.z * vb.z; acc[2][3] += qa.z * vb.w;
        acc[3][0] += qa.w * vb.x; acc[3][1] += qa.w * vb.y; acc[3][2] += qa.w * vb.z; acc[3][3] += qa.w * vb.w;
      }
    }

    // epilogue: scale by vocab inv-norm, stage sim tile, per-row top-8 insert
    __syncthreads();
    float* simtile = lds;                            // [64][65], aliases QT/VT
    float iv[4];
#pragma unroll
    for (int j = 0; j < 4; ++j) iv[j] = invv[cbase + tx * 4 + j];
#pragma unroll
    for (int i = 0; i < 4; ++i)
#pragma unroll
      for (int j = 0; j < 4; ++j)
        simtile[(ty * 4 + i) * 65 + tx * 4 + j] = acc[i][j] * iv[j];
    __syncthreads();
    if (tid < TR) {
      int r = tid;
      float tmin = tval[r][K - 1];
      for (int c = 0; c < TC; ++c) {
        float v = simtile[r * 65 + c];
        if (v > tmin) {                              // strict >: earlier index wins ties
          int j = K - 1;
          while (j > 0 && tval[r][j - 1] < v) {
            tval[r][j] = tval[r][j - 1]; tidx[r][j] = tidx[r][j - 1]; --j;
          }
          tval[r][j] = v; tidx[r][j] = cbase + c;
          tmin = tval[r][K - 1];
        }
      }
    }
    // next iteration's first __syncthreads() protects simtile from restaging
  }

  __syncthreads();
  if (tid < TR) {
    int r = tid;
#pragma unroll
    for (int j = 0; j < K; ++j) {
      int o = (slice * K + j) * N + rbase + r;       // [slice][rank][row] -> coalesced
      cand_val[o] = tval[r][j];
      cand_idx[o] = tidx[r][j];
    }
  }
}

// ------------------- merge per-slice candidates, softmax, scatter, token ids
__global__ void merge_kernel(const float* __restrict__ cand_val, const int* __restrict__ cand_idx,
                             float* __restrict__ out) {
  int row = blockIdx.x * blockDim.x + threadIdx.x;   // one thread per row
  float tv[K]; int ti[K];
#pragma unroll
  for (int j = 0; j < K; ++j) { tv[j] = -3.0e38f; ti[j] = 0; }
  for (int e = 0; e < S * K; ++e) {                  // ascending slice => ascending index for ties
    float v = cand_val[e * N + row];
    int  id = cand_idx[e * N + row];
    if (v > tv[K - 1]) {
      bool gt[K];
#pragma unroll
      for (int j = 0; j < K; ++j) gt[j] = (v > tv[j]);
#pragma unroll
      for (int j = K - 1; j >= 1; --j) {             // static-index predicated shift
        float nv = gt[j - 1] ? tv[j - 1] : (gt[j] ? v : tv[j]);
        int   ni = gt[j - 1] ? ti[j - 1] : (gt[j] ? id : ti[j]);
        tv[j] = nv; ti[j] = ni;
      }
      if (gt[0]) { tv[0] = v; ti[0] = id; }
    }
  }
  // softmax over top-8 (T=1), scatter into zeroed probs row
  float m = tv[0];
  float e8[K]; float sum = 0.f;
#pragma unroll
  for (int j = 0; j < K; ++j) { e8[j] = expf(tv[j] - m); sum += e8[j]; }
  float isum = 1.f / sum;
#pragma unroll
  for (int j = 0; j < K; ++j) out[(size_t)row * V + ti[j]] = e8[j] * isum;
  out[(size_t)N * V + row] = (float)ti[0];           // token id as float
}

extern "C" void kernel_launch(void* const* d_in, const int* in_sizes, int n_in,
                              void* d_out, int out_size, void* d_ws, size_t ws_size,
                              hipStream_t stream) {
  const float* emb   = (const float*)d_in[0];
  const float* vocab = (const float*)d_in[1];
  float* out = (float*)d_out;

  float* wsf      = (float*)d_ws;
  float* invq     = wsf;                         // N
  float* invv     = wsf + N;                     // V
  float* cand_val = wsf + N + V;                 // S*K*N
  int*   cand_idx = (int*)(wsf + N + V + S * K * N);

  zero_kernel<<<2048, 256, 0, stream>>>((float4*)d_out, (int)((size_t)N * V / 4));
  rownorm_kernel<<<N, 256, 0, stream>>>(emb, invq);
  rownorm_kernel<<<V, 256, 0, stream>>>(vocab, invv);
  dim3 grid(S, N / TR);
  simtopk_kernel<<<grid, 256, 0, stream>>>(emb, vocab, invq, invv, cand_val, cand_idx);
  merge_kernel<<<N / 256, 256, 0, stream>>>(cand_val, cand_idx, out);
}

// Round 2
// 901.886 us; speedup vs baseline: 6.2082x; 6.2082x over previous
//
#include <hip/hip_runtime.h>
#include <math.h>

typedef unsigned short u16;
typedef unsigned int u32;
typedef float f32x4 __attribute__((ext_vector_type(4)));
typedef short bf16x8 __attribute__((ext_vector_type(8)));
typedef u16 u16x8 __attribute__((ext_vector_type(8)));

static constexpr int N = 4096;         // B*L
static constexpr int D = 1024;
static constexpr int V = 32000;
static constexpr int K = 8;
static constexpr int BM = 128, BN = 128, BK = 64;
static constexpr int S = 25;           // vocab slices
static constexpr int CPS = V / S;      // 1280 cols/slice
static constexpr int NCT = CPS / BN;   // 10 col-tiles/slice
static constexpr int NCAND = S * K;    // 200 approx candidates per row
static constexpr int T16 = 16;         // rescored candidates per row

static_assert(N % BM == 0 && V % S == 0 && CPS % BN == 0, "tiling");

__device__ __forceinline__ u16 f2bf(float f) {
  u32 u = __float_as_uint(f);
  return (u16)((u + 0x7fffu + ((u >> 16) & 1u)) >> 16);
}
__device__ __forceinline__ float bf2f(u16 h) { return __uint_as_float(((u32)h) << 16); }

// ---------------------------------------------------------------- zero probs
__global__ void zero_kernel(float4* __restrict__ p, int n4) {
  int i = blockIdx.x * blockDim.x + threadIdx.x;
  int stride = gridDim.x * blockDim.x;
  float4 z = make_float4(0.f, 0.f, 0.f, 0.f);
  for (; i < n4; i += stride) p[i] = z;
}

// ------------------------------------------------------- inverse row L2 norm
__global__ void rownorm_kernel(const float* __restrict__ x, float* __restrict__ inv) {
  int row = blockIdx.x;
  const float4* xr = reinterpret_cast<const float4*>(x + (size_t)row * D);
  float4 v = xr[threadIdx.x];
  float ss = v.x * v.x + v.y * v.y + v.z * v.z + v.w * v.w;
#pragma unroll
  for (int off = 32; off > 0; off >>= 1) ss += __shfl_down(ss, off, 64);
  __shared__ float wsum[4];
  if ((threadIdx.x & 63) == 0) wsum[threadIdx.x >> 6] = ss;
  __syncthreads();
  if (threadIdx.x == 0) {
    float t = wsum[0] + wsum[1] + wsum[2] + wsum[3];
    inv[row] = 1.0f / fmaxf(sqrtf(t), 1e-12f);
  }
}

// ------------------------------------------- normalize + convert rows to bf16
__global__ void cvt_kernel(const float* __restrict__ x, const float* __restrict__ inv,
                           u16* __restrict__ o, int rows) {
  int i = blockIdx.x * blockDim.x + threadIdx.x;   // 8-elem chunk id
  if (i >= rows * (D / 8)) return;
  int row = i >> 7;                                 // D/8 == 128
  float s = inv[row];
  const float4* src = reinterpret_cast<const float4*>(x) + (size_t)i * 2;
  float4 a = src[0], b = src[1];
  u16x8 r;
  r[0] = f2bf(a.x * s); r[1] = f2bf(a.y * s); r[2] = f2bf(a.z * s); r[3] = f2bf(a.w * s);
  r[4] = f2bf(b.x * s); r[5] = f2bf(b.y * s); r[6] = f2bf(b.z * s); r[7] = f2bf(b.w * s);
  *reinterpret_cast<u16x8*>(o + (size_t)i * 8) = r;
}

// --------------------- bf16 MFMA sims GEMM (128x128 tile) + fused approx top-8
// grid (S, N/BM), 256 threads = 4 waves (2x2), 16x16x32 MFMA, BK=64.
__global__ __launch_bounds__(256, 3)
void simtopk_kernel(const u16* __restrict__ qn, const u16* __restrict__ vn,
                    float* __restrict__ cand_val, int* __restrict__ cand_idx) {
  __shared__ u16 sh[BM * BK + BN * BK];            // 32 KB; aliased as sim tile / merge buf
  u16* a_sh = sh;
  u16* b_sh = sh + BM * BK;

  const int tid = threadIdx.x;
  const int slice = blockIdx.x;
  const int rbase = blockIdx.y * BM;
  const int wid = tid >> 6, l = tid & 63;
  const int wr = wid >> 1, wc = wid & 1;
  const int sr = l >> 3;                           // staging: row within 8-row group
  const int sk = (l & 7) * 8;                      // staging: k elem offset

  float tv[K]; int ti[K];                          // per-thread running top-8 (64 cols/row half)
#pragma unroll
  for (int j = 0; j < K; ++j) { tv[j] = -3.0e38f; ti[j] = -1; }

  for (int ct = 0; ct < NCT; ++ct) {
    const int cbase = slice * CPS + ct * BN;
    f32x4 acc[4][4];
#pragma unroll
    for (int m = 0; m < 4; ++m)
#pragma unroll
      for (int n = 0; n < 4; ++n) acc[m][n] = (f32x4){0.f, 0.f, 0.f, 0.f};

    for (int kk = 0; kk < D / BK; ++kk) {
      __syncthreads();                             // staging area free
      const int kbase = kk * BK;
#pragma unroll
      for (int c = 0; c < 4; ++c) {                // A: rows rbase + wid*32 + c*8 + sr
        int r = wid * 32 + c * 8 + sr;
        const u16* gs = qn + (size_t)(rbase + r) * D + kbase + sk;
        __builtin_amdgcn_global_load_lds((const __attribute__((address_space(1))) void*)gs,
            (__attribute__((address_space(3))) void*)(a_sh + wid * 2048 + c * 512), 16, 0, 0);
      }
#pragma unroll
      for (int c = 0; c < 4; ++c) {                // B: vocab rows cbase + ...
        int r = wid * 32 + c * 8 + sr;
        const u16* gs = vn + (size_t)(cbase + r) * D + kbase + sk;
        __builtin_amdgcn_global_load_lds((const __attribute__((address_space(1))) void*)gs,
            (__attribute__((address_space(3))) void*)(b_sh + wid * 2048 + c * 512), 16, 0, 0);
      }
      __syncthreads();                             // barrier drains vmcnt -> LDS ready
#pragma unroll
      for (int k2 = 0; k2 < 2; ++k2) {
        bf16x8 af[4], bfr[4];
#pragma unroll
        for (int m = 0; m < 4; ++m)
          af[m] = *reinterpret_cast<const bf16x8*>(
              a_sh + (wr * 64 + m * 16 + (l & 15)) * BK + k2 * 32 + (l >> 4) * 8);
#pragma unroll
        for (int n = 0; n < 4; ++n)
          bfr[n] = *reinterpret_cast<const bf16x8*>(
              b_sh + (wc * 64 + n * 16 + (l & 15)) * BK + k2 * 32 + (l >> 4) * 8);
#pragma unroll
        for (int m = 0; m < 4; ++m)
#pragma unroll
          for (int n = 0; n < 4; ++n)
            acc[m][n] = __builtin_amdgcn_mfma_f32_16x16x32_bf16(af[m], bfr[n], acc[m][n], 0, 0, 0);
      }
    }

    // ---- epilogue: stage sim tile (bf16, XOR-swizzled) into aliased LDS, scan top-8
    __syncthreads();
    u16* st = sh;                                  // [128][128] bf16 = 32 KB
#pragma unroll
    for (int m = 0; m < 4; ++m)
#pragma unroll
      for (int n = 0; n < 4; ++n)
#pragma unroll
        for (int j = 0; j < 4; ++j) {
          int row = wr * 64 + m * 16 + (l >> 4) * 4 + j;   // C/D: col=lane&15, row=(lane>>4)*4+reg
          int col = wc * 64 + n * 16 + (l & 15);
          st[row * BN + (col ^ ((row & 7) << 3))] = f2bf(acc[m][n][j]);
        }
    __syncthreads();
    {
      int r = tid >> 1, hf = tid & 1;              // 2 threads per row, 64 cols each
#pragma unroll
      for (int p8 = 0; p8 < 8; ++p8) {
        int pc = hf * 8 + p8;                      // position-chunk (8 elems)
        u16x8 ch = *reinterpret_cast<const u16x8*>(st + r * BN + pc * 8);
        int colbase = cbase + (((pc & 8) | ((pc ^ r) & 7)) << 3);  // undo swizzle
#pragma unroll
        for (int e = 0; e < 8; ++e) {
          float v = bf2f(ch[e]);
          if (v > tv[K - 1]) {
            int id = colbase + e;
            bool g[K];
#pragma unroll
            for (int j = 0; j < K; ++j) g[j] = v > tv[j];
#pragma unroll
            for (int j = K - 1; j >= 1; --j) {
              tv[j] = g[j - 1] ? tv[j - 1] : (g[j] ? v : tv[j]);
              ti[j] = g[j - 1] ? ti[j - 1] : (g[j] ? id : ti[j]);
            }
            if (g[0]) { tv[0] = v; ti[0] = id; }
          }
        }
      }
    }
  }

  // ---- merge the 2 half-row scanners -> per-slice top-8 per row
  __syncthreads();
  float* mv = (float*)sh;                          // 2048 floats (8 KB)
  int* mi = (int*)sh + 2048;                       // 2048 ints (8 KB)
#pragma unroll
  for (int j = 0; j < K; ++j) { mv[tid * K + j] = tv[j]; mi[tid * K + j] = ti[j]; }
  __syncthreads();
  if (tid < BM) {
    float fv[K]; int fi[K];
#pragma unroll
    for (int j = 0; j < K; ++j) { fv[j] = -3.0e38f; fi[j] = -1; }
#pragma unroll
    for (int t = 0; t < 2; ++t)
#pragma unroll
      for (int j2 = 0; j2 < K; ++j2) {
        float v = mv[(tid * 2 + t) * K + j2];
        int id = mi[(tid * 2 + t) * K + j2];
        if (v > fv[K - 1]) {
          bool g[K];
#pragma unroll
          for (int j = 0; j < K; ++j) g[j] = v > fv[j];
#pragma unroll
          for (int j = K - 1; j >= 1; --j) {
            fv[j] = g[j - 1] ? fv[j - 1] : (g[j] ? v : fv[j]);
            fi[j] = g[j - 1] ? fi[j - 1] : (g[j] ? id : fi[j]);
          }
          if (g[0]) { fv[0] = v; fi[0] = id; }
        }
      }
    int row = rbase + tid;
#pragma unroll
    for (int j = 0; j < K; ++j) {
      cand_val[(size_t)row * NCAND + slice * K + j] = fv[j];
      cand_idx[(size_t)row * NCAND + slice * K + j] = fi[j];
    }
  }
}

// ------- approx top-16 merge + exact fp32 rescore + top-8 + softmax (1 wave/row)
__global__ __launch_bounds__(256)
void rescore_kernel(const float* __restrict__ cand_val, const int* __restrict__ cand_idx,
                    const float* __restrict__ emb, const float* __restrict__ vocab,
                    const float* __restrict__ invq, const float* __restrict__ invv,
                    float* __restrict__ res_p, int* __restrict__ res_i) {
  const int tid = threadIdx.x, wid = tid >> 6, l = tid & 63;
  const int row = blockIdx.x * 4 + wid;

  float4 q[4];                                     // emb row: lane l holds float4s t*64+l
#pragma unroll
  for (int t = 0; t < 4; ++t)
    q[t] = *(reinterpret_cast<const float4*>(emb + (size_t)row * D) + t * 64 + l);
  float iqr = invq[row];

  float lv[4]; int li[4];                          // 4 candidates per lane (200 total)
#pragma unroll
  for (int t = 0; t < 4; ++t) {
    int e = l * 4 + t;
    bool ok = e < NCAND;
    lv[t] = ok ? cand_val[(size_t)row * NCAND + e] : -3.0e38f;
    li[t] = ok ? cand_idx[(size_t)row * NCAND + e] : 0x7fffffff;
  }

  int cidx[T16];                                   // approx top-16 by iterative extraction
#pragma unroll
  for (int jr = 0; jr < T16; ++jr) {
    float bv = lv[0]; int bi = li[0];
#pragma unroll
    for (int t = 1; t < 4; ++t)
      if (lv[t] > bv || (lv[t] == bv && li[t] < bi)) { bv = lv[t]; bi = li[t]; }
#pragma unroll
    for (int off = 32; off > 0; off >>= 1) {
      float ov = __shfl_xor(bv, off, 64); int oi = __shfl_xor(bi, off, 64);
      if (ov > bv || (ov == bv && oi < bi)) { bv = ov; bi = oi; }
    }
    cidx[jr] = bi;
#pragma unroll
    for (int t = 0; t < 4; ++t) if (li[t] == bi) lv[t] = -3.0e38f;
  }

  float sv[T16];                                   // exact fp32 cosine for each candidate
#pragma unroll
  for (int jr = 0; jr < T16; ++jr) {
    int ix = cidx[jr];
    const float4* vr = reinterpret_cast<const float4*>(vocab + (size_t)ix * D);
    float s = 0.f;
#pragma unroll
    for (int t = 0; t < 4; ++t) {
      float4 vv = vr[t * 64 + l];
      s += q[t].x * vv.x + q[t].y * vv.y + q[t].z * vv.z + q[t].w * vv.w;
    }
#pragma unroll
    for (int off = 32; off > 0; off >>= 1) s += __shfl_xor(s, off, 64);
    sv[jr] = s * iqr * invv[ix];
  }

  float pv[K]; int pi[K];                          // exact top-8, idx-asc on ties
#pragma unroll
  for (int r8 = 0; r8 < K; ++r8) {
    float bv = sv[0]; int bi = cidx[0];
#pragma unroll
    for (int jr = 1; jr < T16; ++jr)
      if (sv[jr] > bv || (sv[jr] == bv && cidx[jr] < bi)) { bv = sv[jr]; bi = cidx[jr]; }
    pv[r8] = bv; pi[r8] = bi;
#pragma unroll
    for (int jr = 0; jr < T16; ++jr) if (cidx[jr] == bi) sv[jr] = -3.0e38f;
  }

  float m = pv[0], sum = 0.f, e8[K];
#pragma unroll
  for (int j = 0; j < K; ++j) { e8[j] = expf(pv[j] - m); sum += e8[j]; }
  float isum = 1.f / sum;
  if (l == 0) {
#pragma unroll
    for (int j = 0; j < K; ++j) {
      res_p[row * K + j] = e8[j] * isum;
      res_i[row * K + j] = pi[j];
    }
  }
}

// --------------------------------------------- final scatter into zeroed probs
__global__ void scatter_kernel(const float* __restrict__ res_p, const int* __restrict__ res_i,
                               float* __restrict__ out) {
  int row = blockIdx.x * blockDim.x + threadIdx.x;
#pragma unroll
  for (int j = 0; j < K; ++j) out[(size_t)row * V + res_i[row * K + j]] = res_p[row * K + j];
  out[(size_t)N * V + row] = (float)res_i[row * K];  // token id = exact argmax
}

extern "C" void kernel_launch(void* const* d_in, const int* in_sizes, int n_in,
                              void* d_out, int out_size, void* d_ws, size_t ws_size,
                              hipStream_t stream) {
  const float* emb   = (const float*)d_in[0];
  const float* vocab = (const float*)d_in[1];
  float* out = (float*)d_out;

  // scratch carved out of d_out (524 MB probs region; zeroed after use)
  u16* qn = (u16*)d_out;                                   // 8 MB normalized bf16 Q
  u16* vn = qn + (size_t)N * D;                            // 62.5 MB normalized bf16 V
  float* cand_val = (float*)((char*)d_out + 83886080);     // 80 MiB offset, 3.125 MB
  int*   cand_idx = (int*)((char*)d_out + 83886080 + (size_t)N * NCAND * 4);

  float* wsf   = (float*)d_ws;
  float* invq  = wsf;                                      // N
  float* invv  = wsf + N;                                  // V
  float* res_p = wsf + N + V;                              // N*K
  int*   res_i = (int*)(wsf + N + V + N * K);              // N*K

  rownorm_kernel<<<N, 256, 0, stream>>>(emb, invq);
  rownorm_kernel<<<V, 256, 0, stream>>>(vocab, invv);
  cvt_kernel<<<(N * (D / 8)) / 256, 256, 0, stream>>>(emb, invq, qn, N);
  cvt_kernel<<<(V * (D / 8)) / 256, 256, 0, stream>>>(vocab, invv, vn, V);
  simtopk_kernel<<<dim3(S, N / BM), 256, 0, stream>>>(qn, vn, cand_val, cand_idx);
  rescore_kernel<<<N / 4, 256, 0, stream>>>(cand_val, cand_idx, emb, vocab, invq, invv, res_p, res_i);
  zero_kernel<<<2048, 256, 0, stream>>>((float4*)d_out, (int)((size_t)N * V / 4));
  scatter_kernel<<<N / 256, 256, 0, stream>>>(res_p, res_i, out);
}

// Round 3
// 672.129 us; speedup vs baseline: 8.3303x; 1.3418x over previous
//
#include <hip/hip_runtime.h>
#include <math.h>

typedef unsigned short u16;
typedef unsigned int u32;
typedef float f32x4 __attribute__((ext_vector_type(4)));
typedef short bf16x8 __attribute__((ext_vector_type(8)));
typedef u16 u16x8 __attribute__((ext_vector_type(8)));
typedef u16 u16x4 __attribute__((ext_vector_type(4)));

static constexpr int N = 4096;         // B*L
static constexpr int D = 1024;
static constexpr int V = 32000;
static constexpr int K = 8;
static constexpr int BM = 128, BN = 128, BK = 64;
static constexpr int S = 50;           // vocab slices
static constexpr int CPS = V / S;      // 640 cols/slice
static constexpr int NCT = CPS / BN;   // 5 col-tiles/slice
static constexpr int NCAND = S * K;    // 400 approx candidates per row
static constexpr int T16 = 16;         // rescored candidates per row
static constexpr int CPL = 7;          // rescore candidates per lane (64*7 >= 400)

static_assert(N % BM == 0 && V % S == 0 && CPS % BN == 0, "tiling");

__device__ __forceinline__ u16 f2bf(float f) {
  u32 u = __float_as_uint(f);
  return (u16)((u + 0x7fffu + ((u >> 16) & 1u)) >> 16);
}
__device__ __forceinline__ float bf2f(u16 h) { return __uint_as_float(((u32)h) << 16); }

// ---------------------------------------------------------------- zero probs
__global__ void zero_kernel(float4* __restrict__ p, int n4) {
  int i = blockIdx.x * blockDim.x + threadIdx.x;
  int stride = gridDim.x * blockDim.x;
  float4 z = make_float4(0.f, 0.f, 0.f, 0.f);
  for (; i < n4; i += stride) p[i] = z;
}

// ---------------- fused: inverse L2 norm + normalized bf16 copy (one fp32 read)
__global__ void normcvt_kernel(const float* __restrict__ x, float* __restrict__ inv,
                               u16* __restrict__ o) {
  int row = blockIdx.x;
  const float4* xr = reinterpret_cast<const float4*>(x + (size_t)row * D);
  float4 v = xr[threadIdx.x];                      // 256 thr * 4 = 1024 elems
  float ss = v.x * v.x + v.y * v.y + v.z * v.z + v.w * v.w;
#pragma unroll
  for (int off = 32; off > 0; off >>= 1) ss += __shfl_down(ss, off, 64);
  __shared__ float wsum[4];
  if ((threadIdx.x & 63) == 0) wsum[threadIdx.x >> 6] = ss;
  __syncthreads();
  __shared__ float s_inv;
  if (threadIdx.x == 0) {
    float t = wsum[0] + wsum[1] + wsum[2] + wsum[3];
    float iv = 1.0f / fmaxf(sqrtf(t), 1e-12f);
    inv[row] = iv;
    s_inv = iv;
  }
  __syncthreads();
  float s = s_inv;
  u16x4 r;
  r[0] = f2bf(v.x * s); r[1] = f2bf(v.y * s); r[2] = f2bf(v.z * s); r[3] = f2bf(v.w * s);
  *reinterpret_cast<u16x4*>(o + (size_t)row * D + threadIdx.x * 4) = r;
}

// --------------------- bf16 MFMA sims GEMM (128x128 tile) + fused approx top-8
// grid (S, N/BM), 256 threads = 4 waves (2x2), 16x16x32 MFMA, BK=64.
// LDS A/B tiles XOR-swizzled: stored[r][c] = global[r][c ^ ((r&7)<<3)] (8-elem slots),
// achieved by pre-swizzling the GLOBAL source (global_load_lds dest must stay linear).
__global__ __launch_bounds__(256, 4)
void simtopk_kernel(const u16* __restrict__ qn, const u16* __restrict__ vn,
                    float* __restrict__ cand_val, int* __restrict__ cand_idx) {
  __shared__ u16 sh[BM * BK + BN * BK];            // 32 KB; aliased as sim tile / merge buf
  u16* a_sh = sh;
  u16* b_sh = sh + BM * BK;

  const int tid = threadIdx.x;
  const int slice = blockIdx.x;
  const int rbase = blockIdx.y * BM;
  const int wid = tid >> 6, l = tid & 63;
  const int wr = wid >> 1, wc = wid & 1;
  const int sr = l >> 3;                           // staging: row within 8-row group
  const int sk = (((l & 7) ^ (l >> 3)) << 3);      // staging: PRE-SWIZZLED k elem offset

  float tv[K]; int ti[K];                          // per-thread running top-8 (half row)
#pragma unroll
  for (int j = 0; j < K; ++j) { tv[j] = -3.0e38f; ti[j] = -1; }

  for (int ct = 0; ct < NCT; ++ct) {
    const int cbase = slice * CPS + ct * BN;
    f32x4 acc[4][4];
#pragma unroll
    for (int m = 0; m < 4; ++m)
#pragma unroll
      for (int n = 0; n < 4; ++n) acc[m][n] = (f32x4){0.f, 0.f, 0.f, 0.f};

    for (int kk = 0; kk < D / BK; ++kk) {
      __syncthreads();                             // staging area free
      const int kbase = kk * BK;
#pragma unroll
      for (int c = 0; c < 4; ++c) {                // A rows: rbase + wid*32 + c*8 + sr
        int r = wid * 32 + c * 8 + sr;
        const u16* gs = qn + (size_t)(rbase + r) * D + kbase + sk;
        __builtin_amdgcn_global_load_lds((const __attribute__((address_space(1))) void*)gs,
            (__attribute__((address_space(3))) void*)(a_sh + wid * 2048 + c * 512), 16, 0, 0);
      }
#pragma unroll
      for (int c = 0; c < 4; ++c) {                // B rows: cbase + wid*32 + c*8 + sr
        int r = wid * 32 + c * 8 + sr;
        const u16* gs = vn + (size_t)(cbase + r) * D + kbase + sk;
        __builtin_amdgcn_global_load_lds((const __attribute__((address_space(1))) void*)gs,
            (__attribute__((address_space(3))) void*)(b_sh + wid * 2048 + c * 512), 16, 0, 0);
      }
      __syncthreads();                             // drains vmcnt -> LDS ready
#pragma unroll
      for (int k2 = 0; k2 < 2; ++k2) {
        bf16x8 af[4], bfr[4];
        const int kofs = k2 * 32 + (l >> 4) * 8;
#pragma unroll
        for (int m = 0; m < 4; ++m) {
          int row = wr * 64 + m * 16 + (l & 15);
          af[m] = *reinterpret_cast<const bf16x8*>(
              a_sh + row * BK + (kofs ^ ((row & 7) << 3)));
        }
#pragma unroll
        for (int n = 0; n < 4; ++n) {
          int row = wc * 64 + n * 16 + (l & 15);
          bfr[n] = *reinterpret_cast<const bf16x8*>(
              b_sh + row * BK + (kofs ^ ((row & 7) << 3)));
        }
#pragma unroll
        for (int m = 0; m < 4; ++m)
#pragma unroll
          for (int n = 0; n < 4; ++n)
            acc[m][n] = __builtin_amdgcn_mfma_f32_16x16x32_bf16(af[m], bfr[n], acc[m][n], 0, 0, 0);
      }
    }

    // ---- epilogue: stage sim tile bf16 (swizzled 16B chunks) into aliased LDS
    __syncthreads();
    u16* st = sh;                                  // [128][128] bf16 = 32 KB
#pragma unroll
    for (int m = 0; m < 4; ++m)
#pragma unroll
      for (int n = 0; n < 4; ++n)
#pragma unroll
        for (int j = 0; j < 4; ++j) {
          int row = wr * 64 + m * 16 + (l >> 4) * 4 + j;   // C/D: col=lane&15, row=(l>>4)*4+reg
          int col = wc * 64 + n * 16 + (l & 15);
          int fw = (row >> 2) & 15;
          st[row * BN + (col ^ (fw << 3))] = f2bf(acc[m][n][j]);
        }
    __syncthreads();
    {
      int r = tid >> 1, hf = tid & 1;              // 2 threads per row, 64 cols each
      int f = (r >> 2) & 15;
      float tmin = tv[K - 1];
#pragma unroll
      for (int p8 = 0; p8 < 8; ++p8) {
        int pc = hf * 8 + ((p8 + (r & 7)) & 7);    // phase-rotated chunk (bank spread)
        u16x8 ch = *reinterpret_cast<const u16x8*>(st + r * BN + pc * 8);
        float e[8];
#pragma unroll
        for (int q = 0; q < 8; ++q) e[q] = bf2f(ch[q]);
        float mx = fmaxf(fmaxf(fmaxf(e[0], e[1]), fmaxf(e[2], e[3])),
                         fmaxf(fmaxf(e[4], e[5]), fmaxf(e[6], e[7])));
        if (mx > tmin) {
          int colbase = cbase + ((pc ^ f) << 3);   // undo swizzle
#pragma unroll
          for (int q = 0; q < 8; ++q) {
            float v = e[q];
            if (v > tmin) {
              int id = colbase + q;
              bool g[K];
#pragma unroll
              for (int j = 0; j < K; ++j) g[j] = v > tv[j];
#pragma unroll
              for (int j = K - 1; j >= 1; --j) {
                tv[j] = g[j - 1] ? tv[j - 1] : (g[j] ? v : tv[j]);
                ti[j] = g[j - 1] ? ti[j - 1] : (g[j] ? id : ti[j]);
              }
              if (g[0]) { tv[0] = v; ti[0] = id; }
              tmin = tv[K - 1];
            }
          }
        }
      }
    }
  }

  // ---- merge the 2 half-row scanners -> per-slice top-8 per row
  __syncthreads();
  float* mv = (float*)sh;                          // 2048 floats (8 KB)
  int* mi = (int*)sh + 2048;                       // 2048 ints (8 KB)
#pragma unroll
  for (int j = 0; j < K; ++j) { mv[tid * K + j] = tv[j]; mi[tid * K + j] = ti[j]; }
  __syncthreads();
  if (tid < BM) {
    float fv[K]; int fi[K];
#pragma unroll
    for (int j = 0; j < K; ++j) { fv[j] = -3.0e38f; fi[j] = -1; }
#pragma unroll
    for (int t = 0; t < 2; ++t)
#pragma unroll
      for (int j2 = 0; j2 < K; ++j2) {
        float v = mv[(tid * 2 + t) * K + j2];
        int id = mi[(tid * 2 + t) * K + j2];
        if (v > fv[K - 1]) {
          bool g[K];
#pragma unroll
          for (int j = 0; j < K; ++j) g[j] = v > fv[j];
#pragma unroll
          for (int j = K - 1; j >= 1; --j) {
            fv[j] = g[j - 1] ? fv[j - 1] : (g[j] ? v : fv[j]);
            fi[j] = g[j - 1] ? fi[j - 1] : (g[j] ? id : fi[j]);
          }
          if (g[0]) { fv[0] = v; fi[0] = id; }
        }
      }
    int row = rbase + tid;
#pragma unroll
    for (int j = 0; j < K; ++j) {
      cand_val[(size_t)row * NCAND + slice * K + j] = fv[j];
      cand_idx[(size_t)row * NCAND + slice * K + j] = fi[j];
    }
  }
}

// ------- approx top-16 merge + exact fp32 rescore + top-8 + softmax (1 wave/row)
__global__ __launch_bounds__(256)
void rescore_kernel(const float* __restrict__ cand_val, const int* __restrict__ cand_idx,
                    const float* __restrict__ emb, const float* __restrict__ vocab,
                    const float* __restrict__ invq, const float* __restrict__ invv,
                    float* __restrict__ res_p, int* __restrict__ res_i) {
  const int tid = threadIdx.x, wid = tid >> 6, l = tid & 63;
  const int row = blockIdx.x * 4 + wid;

  float4 q[4];                                     // emb row: lane l holds float4s t*64+l
#pragma unroll
  for (int t = 0; t < 4; ++t)
    q[t] = *(reinterpret_cast<const float4*>(emb + (size_t)row * D) + t * 64 + l);
  float iqr = invq[row];

  float lv[CPL]; int li[CPL];                      // 7 candidates per lane (448 >= 400)
#pragma unroll
  for (int t = 0; t < CPL; ++t) {
    int e = l * CPL + t;
    bool ok = e < NCAND;
    lv[t] = ok ? cand_val[(size_t)row * NCAND + e] : -3.0e38f;
    li[t] = ok ? cand_idx[(size_t)row * NCAND + e] : 0x7fffffff;
  }

  int cidx[T16];                                   // approx top-16 by iterative extraction
#pragma unroll
  for (int jr = 0; jr < T16; ++jr) {
    float bv = lv[0]; int bi = li[0];
#pragma unroll
    for (int t = 1; t < CPL; ++t)
      if (lv[t] > bv || (lv[t] == bv && li[t] < bi)) { bv = lv[t]; bi = li[t]; }
#pragma unroll
    for (int off = 32; off > 0; off >>= 1) {
      float ov = __shfl_xor(bv, off, 64); int oi = __shfl_xor(bi, off, 64);
      if (ov > bv || (ov == bv && oi < bi)) { bv = ov; bi = oi; }
    }
    cidx[jr] = bi;
#pragma unroll
    for (int t = 0; t < CPL; ++t) if (li[t] == bi) lv[t] = -3.0e38f;
  }

  float sv[T16];                                   // exact fp32 cosine for each candidate
#pragma unroll
  for (int jr = 0; jr < T16; ++jr) {
    int ix = cidx[jr];
    const float4* vr = reinterpret_cast<const float4*>(vocab + (size_t)ix * D);
    float s = 0.f;
#pragma unroll
    for (int t = 0; t < 4; ++t) {
      float4 vv = vr[t * 64 + l];
      s += q[t].x * vv.x + q[t].y * vv.y + q[t].z * vv.z + q[t].w * vv.w;
    }
#pragma unroll
    for (int off = 32; off > 0; off >>= 1) s += __shfl_xor(s, off, 64);
    sv[jr] = s * iqr * invv[ix];
  }

  float pv[K]; int pi[K];                          // exact top-8, idx-asc on ties
#pragma unroll
  for (int r8 = 0; r8 < K; ++r8) {
    float bv = sv[0]; int bi = cidx[0];
#pragma unroll
    for (int jr = 1; jr < T16; ++jr)
      if (sv[jr] > bv || (sv[jr] == bv && cidx[jr] < bi)) { bv = sv[jr]; bi = cidx[jr]; }
    pv[r8] = bv; pi[r8] = bi;
#pragma unroll
    for (int jr = 0; jr < T16; ++jr) if (cidx[jr] == bi) sv[jr] = -3.0e38f;
  }

  float m = pv[0], sum = 0.f, e8[K];
#pragma unroll
  for (int j = 0; j < K; ++j) { e8[j] = expf(pv[j] - m); sum += e8[j]; }
  float isum = 1.f / sum;
  if (l == 0) {
#pragma unroll
    for (int j = 0; j < K; ++j) {
      res_p[row * K + j] = e8[j] * isum;
      res_i[row * K + j] = pi[j];
    }
  }
}

// --------------------------------------------- final scatter into zeroed probs
__global__ void scatter_kernel(const float* __restrict__ res_p, const int* __restrict__ res_i,
                               float* __restrict__ out) {
  int row = blockIdx.x * blockDim.x + threadIdx.x;
#pragma unroll
  for (int j = 0; j < K; ++j) out[(size_t)row * V + res_i[row * K + j]] = res_p[row * K + j];
  out[(size_t)N * V + row] = (float)res_i[row * K];  // token id = exact argmax
}

extern "C" void kernel_launch(void* const* d_in, const int* in_sizes, int n_in,
                              void* d_out, int out_size, void* d_ws, size_t ws_size,
                              hipStream_t stream) {
  const float* emb   = (const float*)d_in[0];
  const float* vocab = (const float*)d_in[1];
  float* out = (float*)d_out;

  // scratch carved out of d_out (524 MB probs region; zeroed after use)
  u16* qn = (u16*)d_out;                                   // 8 MB normalized bf16 Q
  u16* vn = qn + (size_t)N * D;                            // 62.5 MiB normalized bf16 V
  float* cand_val = (float*)((char*)d_out + 83886080);     // 80 MiB offset, 6.25 MiB
  int*   cand_idx = (int*)((char*)d_out + 83886080 + (size_t)N * NCAND * 4);

  float* wsf   = (float*)d_ws;
  float* invq  = wsf;                                      // N
  float* invv  = wsf + N;                                  // V
  float* res_p = wsf + N + V;                              // N*K
  int*   res_i = (int*)(wsf + N + V + N * K);              // N*K

  normcvt_kernel<<<N, 256, 0, stream>>>(emb, invq, qn);
  normcvt_kernel<<<V, 256, 0, stream>>>(vocab, invv, vn);
  simtopk_kernel<<<dim3(S, N / BM), 256, 0, stream>>>(qn, vn, cand_val, cand_idx);
  rescore_kernel<<<N / 4, 256, 0, stream>>>(cand_val, cand_idx, emb, vocab, invq, invv, res_p, res_i);
  zero_kernel<<<2048, 256, 0, stream>>>((float4*)d_out, (int)((size_t)N * V / 4));
  scatter_kernel<<<N / 256, 256, 0, stream>>>(res_p, res_i, out);
}

// Round 4
// 618.884 us; speedup vs baseline: 9.0470x; 1.0860x over previous
//
#include <hip/hip_runtime.h>
#include <math.h>

typedef unsigned short u16;
typedef unsigned int u32;
typedef float f32x16 __attribute__((ext_vector_type(16)));
typedef short bf16x8 __attribute__((ext_vector_type(8)));
typedef u16 u16x4 __attribute__((ext_vector_type(4)));

static constexpr int N = 4096;         // B*L
static constexpr int D = 1024;
static constexpr int V = 32000;
static constexpr int K = 8;
static constexpr int BM = 128, BN = 128, BK = 64;
static constexpr int S = 50;           // vocab slices
static constexpr int CPS = V / S;      // 640 cols/slice (fits 10-bit cid)
static constexpr int NCT = CPS / BN;   // 5 col-tiles/slice
static constexpr int NCAND = S * K;    // 400 approx candidates per row
static constexpr int T16 = 16;         // rescored candidates per row
static constexpr int CPL = 7;          // rescore candidates per lane (64*7 >= 400)
static constexpr int GRID = S * (N / BM);  // 1600 (multiple of 8 -> bijective swizzle)
static constexpr u32 PSENT = 0x00800000u;  // packed(-3.4e38), unsigned-min sentinel

static_assert(N % BM == 0 && V % S == 0 && CPS % BN == 0 && GRID % 8 == 0, "tiling");

__device__ __forceinline__ u16 f2bf(float f) {
  u32 u = __float_as_uint(f);
  return (u16)((u + 0x7fffu + ((u >> 16) & 1u)) >> 16);
}
// monotone f32 -> sortable u32
__device__ __forceinline__ u32 flipbits(float v) {
  u32 u = __float_as_uint(v);
  return u ^ (((u32)((int)u >> 31)) | 0x80000000u);
}
// upper bound of packed slot's value
__device__ __forceinline__ float unpackval(u32 p) {
  u32 s = p | 1023u;
  u32 u = (s & 0x80000000u) ? (s ^ 0x80000000u) : ~s;
  return __uint_as_float(u);
}
// descending-sorted 8-slot insert, unsigned compare
__device__ __forceinline__ void insert8(u32 pv[K], u32 x) {
  if (x <= pv[K - 1]) return;
  bool g[K];
#pragma unroll
  for (int j = 0; j < K; ++j) g[j] = x > pv[j];
#pragma unroll
  for (int j = K - 1; j >= 1; --j)
    pv[j] = g[j - 1] ? pv[j - 1] : (g[j] ? x : pv[j]);
  if (g[0]) pv[0] = x;
}

// ---------------------------------------------------------------- zero probs
__global__ void zero_kernel(float4* __restrict__ p, int n4) {
  int i = blockIdx.x * blockDim.x + threadIdx.x;
  int stride = gridDim.x * blockDim.x;
  float4 z = make_float4(0.f, 0.f, 0.f, 0.f);
  for (; i < n4; i += stride) p[i] = z;
}

// ---------------- fused: inverse L2 norm + normalized bf16 copy (one fp32 read)
__global__ void normcvt_kernel(const float* __restrict__ x, float* __restrict__ inv,
                               u16* __restrict__ o) {
  int row = blockIdx.x;
  const float4* xr = reinterpret_cast<const float4*>(x + (size_t)row * D);
  float4 v = xr[threadIdx.x];
  float ss = v.x * v.x + v.y * v.y + v.z * v.z + v.w * v.w;
#pragma unroll
  for (int off = 32; off > 0; off >>= 1) ss += __shfl_down(ss, off, 64);
  __shared__ float wsum[4];
  if ((threadIdx.x & 63) == 0) wsum[threadIdx.x >> 6] = ss;
  __syncthreads();
  __shared__ float s_inv;
  if (threadIdx.x == 0) {
    float t = wsum[0] + wsum[1] + wsum[2] + wsum[3];
    float iv = 1.0f / fmaxf(sqrtf(t), 1e-12f);
    inv[row] = iv;
    s_inv = iv;
  }
  __syncthreads();
  float s = s_inv;
  u16x4 r;
  r[0] = f2bf(v.x * s); r[1] = f2bf(v.y * s); r[2] = f2bf(v.z * s); r[3] = f2bf(v.w * s);
  *reinterpret_cast<u16x4*>(o + (size_t)row * D + threadIdx.x * 4) = r;
}

// ------- bf16 MFMA sims (SWAPPED operands: A=vocab, B=query) + in-register top-8
// 1-D grid 1600, XCD-swizzled. 256 thr = 4 waves (wr=vocab half, wc=query half).
// mfma_f32_32x32x16: C col = lane&31 = q-row; C row = (reg&3)+8*(reg>>2)+4*(l>>5) = vocab col.
// Each lane owns 2 q-rows x 32 vocab cols per tile -> top-8 scan fully in registers.
__global__ __launch_bounds__(256, 3)
void simtopk_kernel(const u16* __restrict__ qn, const u16* __restrict__ vn,
                    u32* __restrict__ cand) {
  __shared__ u16 sh[BM * BK + BN * BK];            // 32 KB; aliased as merge buf
  u16* a_sh = sh;                                  // query tile [128][64]
  u16* b_sh = sh + BM * BK;                        // vocab tile [128][64]

  const int tid = threadIdx.x;
  const int bid = blockIdx.x;
  const int wg = (bid & 7) * (GRID / 8) + (bid >> 3);  // XCD gets contiguous slices
  const int slice = wg >> 5;                       // wg / 32
  const int rbase = (wg & 31) * BM;
  const int wid = tid >> 6, l = tid & 63;
  const int wr = wid >> 1, wc = wid & 1;
  const int h = l >> 5, lid = l & 31;
  const int sr = l >> 3;                           // staging row in 8-row group
  const int sk = (((l & 7) ^ (l >> 3)) << 3);      // pre-swizzled global k offset

  u32 pv[2][K];                                    // packed top-8 per owned q-row
#pragma unroll
  for (int n = 0; n < 2; ++n)
#pragma unroll
    for (int j = 0; j < K; ++j) pv[n][j] = PSENT;
  float tminf[2] = {-3.0e38f, -3.0e38f};

  for (int ct = 0; ct < NCT; ++ct) {
    const int cb = ct * BN;                        // col-in-slice base
    f32x16 acc[2][2];
#pragma unroll
    for (int m = 0; m < 2; ++m)
#pragma unroll
      for (int n = 0; n < 2; ++n)
#pragma unroll
        for (int r = 0; r < 16; ++r) acc[m][n][r] = 0.f;

    for (int kk = 0; kk < D / BK; ++kk) {
      __syncthreads();                             // staging area free
      const int kbase = kk * BK;
#pragma unroll
      for (int c = 0; c < 4; ++c) {                // queries -> a_sh
        int r = wid * 32 + c * 8 + sr;
        const u16* gs = qn + (size_t)(rbase + r) * D + kbase + sk;
        __builtin_amdgcn_global_load_lds((const __attribute__((address_space(1))) void*)gs,
            (__attribute__((address_space(3))) void*)(a_sh + wid * 2048 + c * 512), 16, 0, 0);
      }
#pragma unroll
      for (int c = 0; c < 4; ++c) {                // vocab -> b_sh
        int r = wid * 32 + c * 8 + sr;
        const u16* gs = vn + (size_t)(slice * CPS + cb + r) * D + kbase + sk;
        __builtin_amdgcn_global_load_lds((const __attribute__((address_space(1))) void*)gs,
            (__attribute__((address_space(3))) void*)(b_sh + wid * 2048 + c * 512), 16, 0, 0);
      }
      __syncthreads();                             // drains vmcnt -> LDS ready
#pragma unroll
      for (int t = 0; t < 4; ++t) {                // 4 k-steps of 16
        const int ch = t * 2 + h;                  // 16B chunk index within row
        bf16x8 vf[2], qf[2];
#pragma unroll
        for (int m = 0; m < 2; ++m) {
          int row = wr * 64 + m * 32 + lid;
          vf[m] = *reinterpret_cast<const bf16x8*>(b_sh + row * BK + ((ch ^ (row & 7)) << 3));
        }
#pragma unroll
        for (int n = 0; n < 2; ++n) {
          int row = wc * 64 + n * 32 + lid;
          qf[n] = *reinterpret_cast<const bf16x8*>(a_sh + row * BK + ((ch ^ (row & 7)) << 3));
        }
#pragma unroll
        for (int m = 0; m < 2; ++m)
#pragma unroll
          for (int n = 0; n < 2; ++n)
            acc[m][n] = __builtin_amdgcn_mfma_f32_32x32x16_bf16(vf[m], qf[n], acc[m][n], 0, 0, 0);
      }
    }

    // ---- in-register scan: per n (owned q-row), 2x16 values with col ids from reg
#pragma unroll
    for (int n = 0; n < 2; ++n) {
#pragma unroll
      for (int m = 0; m < 2; ++m) {
        f32x16 a = acc[m][n];
        float x01 = fmaxf(a[0], a[1]),   x23 = fmaxf(a[2], a[3]);
        float x45 = fmaxf(a[4], a[5]),   x67 = fmaxf(a[6], a[7]);
        float x89 = fmaxf(a[8], a[9]),   xab = fmaxf(a[10], a[11]);
        float xcd = fmaxf(a[12], a[13]), xef = fmaxf(a[14], a[15]);
        float mx = fmaxf(fmaxf(fmaxf(x01, x23), fmaxf(x45, x67)),
                         fmaxf(fmaxf(x89, xab), fmaxf(xcd, xef)));
        if (mx > tminf[n]) {
          const int cidb = cb + wr * 64 + m * 32 + 4 * h;
#pragma unroll
          for (int r = 0; r < 16; ++r) {
            float v = a[r];
            if (v > tminf[n]) {
              int cid = cidb + (r & 3) + 8 * (r >> 2);
              u32 p = (flipbits(v) & 0xFFFFFC00u) | (u32)(1023 - cid);
              insert8(pv[n], p);
            }
          }
          tminf[n] = unpackval(pv[n][K - 1]);
        }
      }
    }
  }

  // ---- merge 4 contributors (wr x h) per q-row -> per-slice top-8
  __syncthreads();
  u32* marr = (u32*)sh;                            // [128 rows][4 contrib][8] = 16 KB
#pragma unroll
  for (int n = 0; n < 2; ++n)
#pragma unroll
    for (int j = 0; j < K; ++j)
      marr[((wc * 64 + n * 32 + lid) * 4 + (wr * 2 + h)) * K + j] = pv[n][j];
  __syncthreads();
  if (tid < BM) {
    u32 fv[K];
#pragma unroll
    for (int j = 0; j < K; ++j) fv[j] = PSENT;
#pragma unroll
    for (int c4 = 0; c4 < 4; ++c4)
#pragma unroll
      for (int j = 0; j < K; ++j) insert8(fv, marr[(tid * 4 + c4) * K + j]);
#pragma unroll
    for (int j = 0; j < K; ++j)
      cand[(size_t)(rbase + tid) * NCAND + slice * K + j] = fv[j];
  }
}

// ------- approx top-16 merge + exact fp32 rescore + top-8 + softmax (1 wave/row)
__global__ __launch_bounds__(256)
void rescore_kernel(const u32* __restrict__ cand,
                    const float* __restrict__ emb, const float* __restrict__ vocab,
                    const float* __restrict__ invq, const float* __restrict__ invv,
                    float* __restrict__ res_p, int* __restrict__ res_i) {
  const int tid = threadIdx.x, wid = tid >> 6, l = tid & 63;
  const int row = blockIdx.x * 4 + wid;

  float4 q[4];                                     // emb row: lane l holds float4s t*64+l
#pragma unroll
  for (int t = 0; t < 4; ++t)
    q[t] = *(reinterpret_cast<const float4*>(emb + (size_t)row * D) + t * 64 + l);
  float iqr = invq[row];

  u32 pl[CPL]; int li[CPL];                        // packed candidates + global ids
#pragma unroll
  for (int t = 0; t < CPL; ++t) {
    int e = l * CPL + t;
    bool ok = e < NCAND;
    u32 p = ok ? cand[(size_t)row * NCAND + e] : PSENT;
    pl[t] = ok ? p : 0u;
    li[t] = ok ? ((e >> 3) * CPS + 1023 - (int)(p & 1023u)) : 0x7fffffff;
  }

  int cidx[T16];                                   // approx top-16 by iterative extraction
#pragma unroll
  for (int jr = 0; jr < T16; ++jr) {
    u32 bp = pl[0]; int bi = li[0];
#pragma unroll
    for (int t = 1; t < CPL; ++t)
      if (pl[t] > bp || (pl[t] == bp && li[t] < bi)) { bp = pl[t]; bi = li[t]; }
#pragma unroll
    for (int off = 32; off > 0; off >>= 1) {
      u32 op = (u32)__shfl_xor((int)bp, off, 64); int oi = __shfl_xor(bi, off, 64);
      if (op > bp || (op == bp && oi < bi)) { bp = op; bi = oi; }
    }
    cidx[jr] = bi;
#pragma unroll
    for (int t = 0; t < CPL; ++t) if (li[t] == bi) pl[t] = 0u;
  }

  float sv[T16];                                   // exact fp32 cosine for each candidate
#pragma unroll
  for (int jr = 0; jr < T16; ++jr) {
    int ix = cidx[jr];
    const float4* vr = reinterpret_cast<const float4*>(vocab + (size_t)ix * D);
    float s = 0.f;
#pragma unroll
    for (int t = 0; t < 4; ++t) {
      float4 vv = vr[t * 64 + l];
      s += q[t].x * vv.x + q[t].y * vv.y + q[t].z * vv.z + q[t].w * vv.w;
    }
#pragma unroll
    for (int off = 32; off > 0; off >>= 1) s += __shfl_xor(s, off, 64);
    sv[jr] = s * iqr * invv[ix];
  }

  float pvv[K]; int pii[K];                        // exact top-8, idx-asc on ties
#pragma unroll
  for (int r8 = 0; r8 < K; ++r8) {
    float bv = sv[0]; int bi = cidx[0];
#pragma unroll
    for (int jr = 1; jr < T16; ++jr)
      if (sv[jr] > bv || (sv[jr] == bv && cidx[jr] < bi)) { bv = sv[jr]; bi = cidx[jr]; }
    pvv[r8] = bv; pii[r8] = bi;
#pragma unroll
    for (int jr = 0; jr < T16; ++jr) if (cidx[jr] == bi) sv[jr] = -3.0e38f;
  }

  float m = pvv[0], sum = 0.f, e8[K];
#pragma unroll
  for (int j = 0; j < K; ++j) { e8[j] = expf(pvv[j] - m); sum += e8[j]; }
  float isum = 1.f / sum;
  if (l == 0) {
#pragma unroll
    for (int j = 0; j < K; ++j) {
      res_p[row * K + j] = e8[j] * isum;
      res_i[row * K + j] = pii[j];
    }
  }
}

// --------------------------------------------- final scatter into zeroed probs
__global__ void scatter_kernel(const float* __restrict__ res_p, const int* __restrict__ res_i,
                               float* __restrict__ out) {
  int row = blockIdx.x * blockDim.x + threadIdx.x;
#pragma unroll
  for (int j = 0; j < K; ++j) out[(size_t)row * V + res_i[row * K + j]] = res_p[row * K + j];
  out[(size_t)N * V + row] = (float)res_i[row * K];  // token id = exact argmax
}

extern "C" void kernel_launch(void* const* d_in, const int* in_sizes, int n_in,
                              void* d_out, int out_size, void* d_ws, size_t ws_size,
                              hipStream_t stream) {
  const float* emb   = (const float*)d_in[0];
  const float* vocab = (const float*)d_in[1];
  float* out = (float*)d_out;

  // scratch carved out of d_out (524 MB probs region; zeroed after use)
  u16* qn = (u16*)d_out;                                   // 8 MB normalized bf16 Q
  u16* vn = qn + (size_t)N * D;                            // 64 MB normalized bf16 V
  u32* cand = (u32*)((char*)d_out + 83886080);             // 80 MiB offset, 6.4 MB

  float* wsf   = (float*)d_ws;
  float* invq  = wsf;                                      // N
  float* invv  = wsf + N;                                  // V
  float* res_p = wsf + N + V;                              // N*K
  int*   res_i = (int*)(wsf + N + V + N * K);              // N*K

  normcvt_kernel<<<N, 256, 0, stream>>>(emb, invq, qn);
  normcvt_kernel<<<V, 256, 0, stream>>>(vocab, invv, vn);
  simtopk_kernel<<<GRID, 256, 0, stream>>>(qn, vn, cand);
  rescore_kernel<<<N / 4, 256, 0, stream>>>(cand, emb, vocab, invq, invv, res_p, res_i);
  zero_kernel<<<2048, 256, 0, stream>>>((float4*)d_out, (int)((size_t)N * V / 4));
  scatter_kernel<<<N / 256, 256, 0, stream>>>(res_p, res_i, out);
}

// Round 5
// 610.172 us; speedup vs baseline: 9.1762x; 1.0143x over previous
//
#include <hip/hip_runtime.h>
#include <math.h>

typedef unsigned short u16;
typedef unsigned int u32;
typedef float f32x16 __attribute__((ext_vector_type(16)));
typedef short bf16x8 __attribute__((ext_vector_type(8)));
typedef u16 u16x4 __attribute__((ext_vector_type(4)));

static constexpr int N = 4096;         // B*L
static constexpr int D = 1024;
static constexpr int V = 32000;
static constexpr int K = 8;
static constexpr int BM = 128, BN = 128, BK = 64;
static constexpr int S = 50;           // vocab slices
static constexpr int CPS = V / S;      // 640 cols/slice (fits 10-bit cid)
static constexpr int NCT = CPS / BN;   // 5 col-tiles/slice
static constexpr int NCAND = S * K;    // 400 approx candidates per row
static constexpr int T16 = 16;         // rescored candidates per row
static constexpr int CPL = 7;          // rescore candidates per lane (64*7 >= 400)
static constexpr int GRID = S * (N / BM);  // 1600 (multiple of 8 -> bijective swizzle)
static constexpr int NIT = NCT * (D / BK); // 80 pipelined (ct,kk) items per block
static constexpr u32 PSENT = 0x00800000u;  // packed(-3.4e38), unsigned-min sentinel

// d_out layout: [qn 8MB | vn 62.5MB | pad | cand @80MiB | zero-tail @ZOFS ... N*V*4) [ids]
static constexpr size_t OUT_PROB_BYTES = (size_t)N * V * 4;            // 524,288,000
static constexpr size_t CAND_OFS = 83886080;                           // 80 MiB
static constexpr size_t ZOFS = CAND_OFS + (size_t)N * NCAND * 4;       // 90,439,680 (16B aligned)
static constexpr size_t NZ4 = (OUT_PROB_BYTES - ZOFS) / 16;            // 27,115,520 float4s

static_assert(N % BM == 0 && V % S == 0 && CPS % BN == 0 && GRID % 8 == 0, "tiling");
static_assert(ZOFS % 16 == 0, "align");

__device__ __forceinline__ u16 f2bf(float f) {
  u32 u = __float_as_uint(f);
  return (u16)((u + 0x7fffu + ((u >> 16) & 1u)) >> 16);
}
// monotone f32 -> sortable u32
__device__ __forceinline__ u32 flipbits(float v) {
  u32 u = __float_as_uint(v);
  return u ^ (((u32)((int)u >> 31)) | 0x80000000u);
}
// upper bound of packed slot's value
__device__ __forceinline__ float unpackval(u32 p) {
  u32 s = p | 1023u;
  u32 u = (s & 0x80000000u) ? (s ^ 0x80000000u) : ~s;
  return __uint_as_float(u);
}
// descending-sorted 8-slot insert, unsigned compare
__device__ __forceinline__ void insert8(u32 pv[K], u32 x) {
  if (x <= pv[K - 1]) return;
  bool g[K];
#pragma unroll
  for (int j = 0; j < K; ++j) g[j] = x > pv[j];
#pragma unroll
  for (int j = K - 1; j >= 1; --j)
    pv[j] = g[j - 1] ? pv[j - 1] : (g[j] ? x : pv[j]);
  if (g[0]) pv[0] = x;
}

// ---------------------------------------------------------------- zero (scratch region only)
__global__ void zero_kernel(float4* __restrict__ p, int n4) {
  int i = blockIdx.x * blockDim.x + threadIdx.x;
  int stride = gridDim.x * blockDim.x;
  float4 z = make_float4(0.f, 0.f, 0.f, 0.f);
  for (; i < n4; i += stride) p[i] = z;
}

// ---------------- fused: inverse L2 norm + normalized bf16 copy (one fp32 read)
__global__ void normcvt_kernel(const float* __restrict__ x, float* __restrict__ inv,
                               u16* __restrict__ o) {
  int row = blockIdx.x;
  const float4* xr = reinterpret_cast<const float4*>(x + (size_t)row * D);
  float4 v = xr[threadIdx.x];
  float ss = v.x * v.x + v.y * v.y + v.z * v.z + v.w * v.w;
#pragma unroll
  for (int off = 32; off > 0; off >>= 1) ss += __shfl_down(ss, off, 64);
  __shared__ float wsum[4];
  if ((threadIdx.x & 63) == 0) wsum[threadIdx.x >> 6] = ss;
  __syncthreads();
  __shared__ float s_inv;
  if (threadIdx.x == 0) {
    float t = wsum[0] + wsum[1] + wsum[2] + wsum[3];
    float iv = 1.0f / fmaxf(sqrtf(t), 1e-12f);
    inv[row] = iv;
    s_inv = iv;
  }
  __syncthreads();
  float s = s_inv;
  u16x4 r;
  r[0] = f2bf(v.x * s); r[1] = f2bf(v.y * s); r[2] = f2bf(v.z * s); r[3] = f2bf(v.w * s);
  *reinterpret_cast<u16x4*>(o + (size_t)row * D + threadIdx.x * 4) = r;
}

// ------- bf16 MFMA sims (SWAPPED operands: A=vocab, B=query) + in-register top-8
// Double-buffered LDS + counted vmcnt(8) software pipeline (T3/T4): stage(it+1)
// issued before waiting on stage(it); loads never drained to 0 in the main loop.
// Fused tail-region zero-fill: one float4 zero-store/thread/iter, issued OLDEST
// in vmcnt order (before the stage) so the counted wait semantics stay exact.
__global__ __launch_bounds__(256, 2)
void simtopk_kernel(const u16* __restrict__ qn, const u16* __restrict__ vn,
                    u32* __restrict__ cand, float4* __restrict__ zout) {
  __shared__ __align__(16) u16 sh[4 * BM * BK];    // 64 KB: buf0 {A,B} | buf1 {A,B}

  const int tid = threadIdx.x;
  const int bid = blockIdx.x;
  const int wg = (bid & 7) * (GRID / 8) + (bid >> 3);  // XCD gets contiguous slices
  const int slice = wg >> 5;
  const int rbase = (wg & 31) * BM;
  const int wid = tid >> 6, l = tid & 63;
  const int wr = wid >> 1, wc = wid & 1;
  const int h = l >> 5, lid = l & 31;
  const int sr = l >> 3;                           // staging row in 8-row group
  const int sk = (((l & 7) ^ (l >> 3)) << 3);      // pre-swizzled global k offset

  const float4 zf4 = make_float4(0.f, 0.f, 0.f, 0.f);

  u32 pv[2][K];                                    // packed top-8 per owned q-row
#pragma unroll
  for (int n = 0; n < 2; ++n)
#pragma unroll
    for (int j = 0; j < K; ++j) pv[n][j] = PSENT;
  float tminf[2] = {-3.0e38f, -3.0e38f};

  f32x16 acc[2][2];
#pragma unroll
  for (int m = 0; m < 2; ++m)
#pragma unroll
    for (int n = 0; n < 2; ++n)
#pragma unroll
      for (int r = 0; r < 16; ++r) acc[m][n][r] = 0.f;

  auto STAGE = [&](int item, u16* base) {
    const int ct_ = item >> 4, kk_ = item & 15;
    const int kb_ = kk_ * BK;
    u16* a_ = base;                                // query tile [128][64]
    u16* b_ = base + BM * BK;                      // vocab tile [128][64]
#pragma unroll
    for (int c = 0; c < 4; ++c) {
      int r = wid * 32 + c * 8 + sr;
      const u16* gs = qn + (size_t)(rbase + r) * D + kb_ + sk;
      __builtin_amdgcn_global_load_lds((const __attribute__((address_space(1))) void*)gs,
          (__attribute__((address_space(3))) void*)(a_ + wid * 2048 + c * 512), 16, 0, 0);
    }
#pragma unroll
    for (int c = 0; c < 4; ++c) {
      int r = wid * 32 + c * 8 + sr;
      const u16* gs = vn + (size_t)(slice * CPS + ct_ * BN + r) * D + kb_ + sk;
      __builtin_amdgcn_global_load_lds((const __attribute__((address_space(1))) void*)gs,
          (__attribute__((address_space(3))) void*)(b_ + wid * 2048 + c * 512), 16, 0, 0);
    }
  };

  auto COMPUTE = [&](u16* base) {
    u16* a_ = base;
    u16* b_ = base + BM * BK;
    __builtin_amdgcn_s_setprio(1);
#pragma unroll
    for (int t = 0; t < 4; ++t) {                  // 4 k-steps of 16
      const int ch = t * 2 + h;
      bf16x8 vf[2], qf[2];
#pragma unroll
      for (int m = 0; m < 2; ++m) {
        int row = wr * 64 + m * 32 + lid;
        vf[m] = *reinterpret_cast<const bf16x8*>(b_ + row * BK + ((ch ^ (row & 7)) << 3));
      }
#pragma unroll
      for (int n = 0; n < 2; ++n) {
        int row = wc * 64 + n * 32 + lid;
        qf[n] = *reinterpret_cast<const bf16x8*>(a_ + row * BK + ((ch ^ (row & 7)) << 3));
      }
#pragma unroll
      for (int m = 0; m < 2; ++m)
#pragma unroll
        for (int n = 0; n < 2; ++n)
          acc[m][n] = __builtin_amdgcn_mfma_f32_32x32x16_bf16(vf[m], qf[n], acc[m][n], 0, 0, 0);
    }
    __builtin_amdgcn_s_setprio(0);
  };

  auto SCAN = [&](int ct_) {                       // in-register top-8 scan + acc reset
    const int cb = ct_ * BN;
#pragma unroll
    for (int n = 0; n < 2; ++n) {
#pragma unroll
      for (int m = 0; m < 2; ++m) {
        f32x16 a = acc[m][n];
        float x01 = fmaxf(a[0], a[1]),   x23 = fmaxf(a[2], a[3]);
        float x45 = fmaxf(a[4], a[5]),   x67 = fmaxf(a[6], a[7]);
        float x89 = fmaxf(a[8], a[9]),   xab = fmaxf(a[10], a[11]);
        float xcd = fmaxf(a[12], a[13]), xef = fmaxf(a[14], a[15]);
        float mx = fmaxf(fmaxf(fmaxf(x01, x23), fmaxf(x45, x67)),
                         fmaxf(fmaxf(x89, xab), fmaxf(xcd, xef)));
        if (mx > tminf[n]) {
          const int cidb = cb + wr * 64 + m * 32 + 4 * h;
#pragma unroll
          for (int r = 0; r < 16; ++r) {
            float v = a[r];
            if (v > tminf[n]) {
              int cid = cidb + (r & 3) + 8 * (r >> 2);
              u32 p = (flipbits(v) & 0xFFFFFC00u) | (u32)(1023 - cid);
              insert8(pv[n], p);
            }
          }
          tminf[n] = unpackval(pv[n][K - 1]);
        }
      }
    }
#pragma unroll
    for (int m = 0; m < 2; ++m)
#pragma unroll
      for (int n = 0; n < 2; ++n)
#pragma unroll
        for (int r = 0; r < 16; ++r) acc[m][n][r] = 0.f;
  };

  // ---- software pipeline over 80 items -------------------------------------
  STAGE(0, sh);                                    // 8 loads in flight
  for (int it = 0; it < NIT - 1; ++it) {
    size_t g = ((size_t)bid * NIT + it) * 256 + tid;   // fused zero-fill (oldest vmem op)
    if (g < NZ4) zout[g] = zf4;
    STAGE(it + 1, sh + (((it + 1) & 1) ? 2 * BM * BK : 0));
    asm volatile("s_waitcnt vmcnt(8)" ::: "memory");   // current buf complete; next in flight
    __builtin_amdgcn_s_barrier();
    __builtin_amdgcn_sched_barrier(0);
    COMPUTE(sh + ((it & 1) ? 2 * BM * BK : 0));
    __builtin_amdgcn_s_barrier();                  // all waves done reading this buf
    __builtin_amdgcn_sched_barrier(0);
    if ((it & 15) == 15) SCAN(it >> 4);            // register-only; overlaps in-flight loads
  }
  {                                                // epilogue: last item
    size_t g = ((size_t)bid * NIT + (NIT - 1)) * 256 + tid;
    if (g < NZ4) zout[g] = zf4;
    asm volatile("s_waitcnt vmcnt(0)" ::: "memory");
    __builtin_amdgcn_s_barrier();
    __builtin_amdgcn_sched_barrier(0);
    COMPUTE(sh + (((NIT - 1) & 1) ? 2 * BM * BK : 0));
    SCAN((NIT - 1) >> 4);
  }

  // ---- merge 4 contributors (wr x h) per q-row -> per-slice top-8
  __syncthreads();
  u32* marr = (u32*)sh;                            // [128 rows][4 contrib][8] = 16 KB
#pragma unroll
  for (int n = 0; n < 2; ++n)
#pragma unroll
    for (int j = 0; j < K; ++j)
      marr[((wc * 64 + n * 32 + lid) * 4 + (wr * 2 + h)) * K + j] = pv[n][j];
  __syncthreads();
  if (tid < BM) {
    u32 fv[K];
#pragma unroll
    for (int j = 0; j < K; ++j) fv[j] = PSENT;
#pragma unroll
    for (int c4 = 0; c4 < 4; ++c4)
#pragma unroll
      for (int j = 0; j < K; ++j) insert8(fv, marr[(tid * 4 + c4) * K + j]);
#pragma unroll
    for (int j = 0; j < K; ++j)
      cand[(size_t)(rbase + tid) * NCAND + slice * K + j] = fv[j];
  }
}

// ------- approx top-16 merge + exact fp32 rescore + top-8 + softmax (1 wave/row)
__global__ __launch_bounds__(256)
void rescore_kernel(const u32* __restrict__ cand,
                    const float* __restrict__ emb, const float* __restrict__ vocab,
                    const float* __restrict__ invq, const float* __restrict__ invv,
                    float* __restrict__ res_p, int* __restrict__ res_i) {
  const int tid = threadIdx.x, wid = tid >> 6, l = tid & 63;
  const int row = blockIdx.x * 4 + wid;

  float4 q[4];                                     // emb row: lane l holds float4s t*64+l
#pragma unroll
  for (int t = 0; t < 4; ++t)
    q[t] = *(reinterpret_cast<const float4*>(emb + (size_t)row * D) + t * 64 + l);
  float iqr = invq[row];

  u32 pl[CPL]; int li[CPL];                        // packed candidates + global ids
#pragma unroll
  for (int t = 0; t < CPL; ++t) {
    int e = l * CPL + t;
    bool ok = e < NCAND;
    u32 p = ok ? cand[(size_t)row * NCAND + e] : PSENT;
    pl[t] = ok ? p : 0u;
    li[t] = ok ? ((e >> 3) * CPS + 1023 - (int)(p & 1023u)) : 0x7fffffff;
  }

  int cidx[T16];                                   // approx top-16 by iterative extraction
#pragma unroll
  for (int jr = 0; jr < T16; ++jr) {
    u32 bp = pl[0]; int bi = li[0];
#pragma unroll
    for (int t = 1; t < CPL; ++t)
      if (pl[t] > bp || (pl[t] == bp && li[t] < bi)) { bp = pl[t]; bi = li[t]; }
#pragma unroll
    for (int off = 32; off > 0; off >>= 1) {
      u32 op = (u32)__shfl_xor((int)bp, off, 64); int oi = __shfl_xor(bi, off, 64);
      if (op > bp || (op == bp && oi < bi)) { bp = op; bi = oi; }
    }
    cidx[jr] = bi;
#pragma unroll
    for (int t = 0; t < CPL; ++t) if (li[t] == bi) pl[t] = 0u;
  }

  float sv[T16];                                   // exact fp32 cosine for each candidate
#pragma unroll
  for (int jr = 0; jr < T16; ++jr) {
    int ix = cidx[jr];
    const float4* vr = reinterpret_cast<const float4*>(vocab + (size_t)ix * D);
    float s = 0.f;
#pragma unroll
    for (int t = 0; t < 4; ++t) {
      float4 vv = vr[t * 64 + l];
      s += q[t].x * vv.x + q[t].y * vv.y + q[t].z * vv.z + q[t].w * vv.w;
    }
#pragma unroll
    for (int off = 32; off > 0; off >>= 1) s += __shfl_xor(s, off, 64);
    sv[jr] = s * iqr * invv[ix];
  }

  float pvv[K]; int pii[K];                        // exact top-8, idx-asc on ties
#pragma unroll
  for (int r8 = 0; r8 < K; ++r8) {
    float bv = sv[0]; int bi = cidx[0];
#pragma unroll
    for (int jr = 1; jr < T16; ++jr)
      if (sv[jr] > bv || (sv[jr] == bv && cidx[jr] < bi)) { bv = sv[jr]; bi = cidx[jr]; }
    pvv[r8] = bv; pii[r8] = bi;
#pragma unroll
    for (int jr = 0; jr < T16; ++jr) if (cidx[jr] == bi) sv[jr] = -3.0e38f;
  }

  float m = pvv[0], sum = 0.f, e8[K];
#pragma unroll
  for (int j = 0; j < K; ++j) { e8[j] = expf(pvv[j] - m); sum += e8[j]; }
  float isum = 1.f / sum;
  if (l == 0) {
#pragma unroll
    for (int j = 0; j < K; ++j) {
      res_p[row * K + j] = e8[j] * isum;
      res_i[row * K + j] = pii[j];
    }
  }
}

// --------------------------------------------- final scatter into zeroed probs
__global__ void scatter_kernel(const float* __restrict__ res_p, const int* __restrict__ res_i,
                               float* __restrict__ out) {
  int row = blockIdx.x * blockDim.x + threadIdx.x;
#pragma unroll
  for (int j = 0; j < K; ++j) out[(size_t)row * V + res_i[row * K + j]] = res_p[row * K + j];
  out[(size_t)N * V + row] = (float)res_i[row * K];  // token id = exact argmax
}

extern "C" void kernel_launch(void* const* d_in, const int* in_sizes, int n_in,
                              void* d_out, int out_size, void* d_ws, size_t ws_size,
                              hipStream_t stream) {
  const float* emb   = (const float*)d_in[0];
  const float* vocab = (const float*)d_in[1];
  float* out = (float*)d_out;

  // scratch carved out of d_out (probs region; re-zeroed before scatter)
  u16* qn = (u16*)d_out;                                   // 8 MB normalized bf16 Q
  u16* vn = qn + (size_t)N * D;                            // 64 MB normalized bf16 V
  u32* cand = (u32*)((char*)d_out + CAND_OFS);             // 6.4 MB
  float4* ztail = (float4*)((char*)d_out + ZOFS);          // zero-fill target in simtopk

  float* wsf   = (float*)d_ws;
  float* invq  = wsf;                                      // N
  float* invv  = wsf + N;                                  // V
  float* res_p = wsf + N + V;                              // N*K
  int*   res_i = (int*)(wsf + N + V + N * K);              // N*K

  normcvt_kernel<<<N, 256, 0, stream>>>(emb, invq, qn);
  normcvt_kernel<<<V, 256, 0, stream>>>(vocab, invv, vn);
  simtopk_kernel<<<GRID, 256, 0, stream>>>(qn, vn, cand, ztail);
  rescore_kernel<<<N / 4, 256, 0, stream>>>(cand, emb, vocab, invq, invv, res_p, res_i);
  zero_kernel<<<2048, 256, 0, stream>>>((float4*)d_out, (int)(ZOFS / 16));  // scratch region
  scatter_kernel<<<N / 256, 256, 0, stream>>>(res_p, res_i, out);
}

// Round 6
// 582.018 us; speedup vs baseline: 9.6201x; 1.0484x over previous
//
#include <hip/hip_runtime.h>
#include <math.h>

typedef unsigned short u16;
typedef unsigned int u32;
typedef float f32x16 __attribute__((ext_vector_type(16)));
typedef short bf16x8 __attribute__((ext_vector_type(8)));
typedef u16 u16x4 __attribute__((ext_vector_type(4)));

static constexpr int N = 4096;         // B*L
static constexpr int D = 1024;
static constexpr int V = 32000;
static constexpr int K = 8;
static constexpr int BM = 128, BN = 128, BK = 64;
static constexpr int S = 50;           // vocab slices
static constexpr int CPS = V / S;      // 640 cols/slice (fits 10-bit cid)
static constexpr int NCT = CPS / BN;   // 5 col-tiles/slice
static constexpr int NCAND = S * K;    // 400 approx candidates per row
static constexpr int T16 = 16;         // rescored candidates per row
static constexpr int CPL = 7;          // rescore candidates per lane (64*7 >= 400)
static constexpr int GRID = S * (N / BM);  // 1600 (multiple of 8 -> bijective swizzle)
static constexpr int NIT = NCT * (D / BK); // 80 (ct,kk) items per block
static constexpr u32 PSENT = 0x00800000u;  // packed(-3.4e38), unsigned-min sentinel

// d_out layout: [qn 8MB | vn 62.5MB | pad | cand @80MiB | zero-tail @ZOFS ... N*V*4) [ids]
static constexpr size_t OUT_PROB_BYTES = (size_t)N * V * 4;            // 524,288,000
static constexpr size_t CAND_OFS = 83886080;                           // 80 MiB
static constexpr size_t ZOFS = CAND_OFS + (size_t)N * NCAND * 4;       // 90,439,680 (16B aligned)
static constexpr size_t NZ4 = (OUT_PROB_BYTES - ZOFS) / 16;            // 27,115,520 float4s

static_assert(N % BM == 0 && V % S == 0 && CPS % BN == 0 && GRID % 8 == 0, "tiling");
static_assert(ZOFS % 16 == 0, "align");

__device__ __forceinline__ u16 f2bf(float f) {
  u32 u = __float_as_uint(f);
  return (u16)((u + 0x7fffu + ((u >> 16) & 1u)) >> 16);
}
// monotone f32 -> sortable u32
__device__ __forceinline__ u32 flipbits(float v) {
  u32 u = __float_as_uint(v);
  return u ^ (((u32)((int)u >> 31)) | 0x80000000u);
}
// upper bound of packed slot's value
__device__ __forceinline__ float unpackval(u32 p) {
  u32 s = p | 1023u;
  u32 u = (s & 0x80000000u) ? (s ^ 0x80000000u) : ~s;
  return __uint_as_float(u);
}
// descending-sorted 8-slot insert, unsigned compare
__device__ __forceinline__ void insert8(u32 pv[K], u32 x) {
  if (x <= pv[K - 1]) return;
  bool g[K];
#pragma unroll
  for (int j = 0; j < K; ++j) g[j] = x > pv[j];
#pragma unroll
  for (int j = K - 1; j >= 1; --j)
    pv[j] = g[j - 1] ? pv[j - 1] : (g[j] ? x : pv[j]);
  if (g[0]) pv[0] = x;
}

// ---------------------------------------------------------------- zero (scratch region only)
__global__ void zero_kernel(float4* __restrict__ p, int n4) {
  int i = blockIdx.x * blockDim.x + threadIdx.x;
  int stride = gridDim.x * blockDim.x;
  float4 z = make_float4(0.f, 0.f, 0.f, 0.f);
  for (; i < n4; i += stride) p[i] = z;
}

// ---------------- fused: inverse L2 norm + normalized bf16 copy (one fp32 read)
__global__ void normcvt_kernel(const float* __restrict__ x, float* __restrict__ inv,
                               u16* __restrict__ o) {
  int row = blockIdx.x;
  const float4* xr = reinterpret_cast<const float4*>(x + (size_t)row * D);
  float4 v = xr[threadIdx.x];
  float ss = v.x * v.x + v.y * v.y + v.z * v.z + v.w * v.w;
#pragma unroll
  for (int off = 32; off > 0; off >>= 1) ss += __shfl_down(ss, off, 64);
  __shared__ float wsum[4];
  if ((threadIdx.x & 63) == 0) wsum[threadIdx.x >> 6] = ss;
  __syncthreads();
  __shared__ float s_inv;
  if (threadIdx.x == 0) {
    float t = wsum[0] + wsum[1] + wsum[2] + wsum[3];
    float iv = 1.0f / fmaxf(sqrtf(t), 1e-12f);
    inv[row] = iv;
    s_inv = iv;
  }
  __syncthreads();
  float s = s_inv;
  u16x4 r;
  r[0] = f2bf(v.x * s); r[1] = f2bf(v.y * s); r[2] = f2bf(v.z * s); r[3] = f2bf(v.w * s);
  *reinterpret_cast<u16x4*>(o + (size_t)row * D + threadIdx.x * 4) = r;
}

// ------- bf16 MFMA sims (SWAPPED operands: A=vocab, B=query) + in-register top-8
// Round-4 structure (single 32KB buffer, barrier-drain per k-step) + fused
// tail-region zero-fill (one float4 store/thread/item, drained by the same
// barrier) + launch_bounds(256,4): 64 AGPR acc + <=64 VGPR = 128/wave -> 4 blocks/CU.
__global__ __launch_bounds__(256, 4)
void simtopk_kernel(const u16* __restrict__ qn, const u16* __restrict__ vn,
                    u32* __restrict__ cand, float4* __restrict__ zout) {
  __shared__ __align__(16) u16 sh[2 * BM * BK];    // 32 KB: {A, B}; aliased as merge buf

  u16* a_sh = sh;                                  // query tile [128][64]
  u16* b_sh = sh + BM * BK;                        // vocab tile [128][64]

  const int tid = threadIdx.x;
  const int bid = blockIdx.x;
  const int wg = (bid & 7) * (GRID / 8) + (bid >> 3);  // XCD gets contiguous slices
  const int slice = wg >> 5;
  const int rbase = (wg & 31) * BM;
  const int wid = tid >> 6, l = tid & 63;
  const int wr = wid >> 1, wc = wid & 1;
  const int h = l >> 5, lid = l & 31;
  const int sr = l >> 3;                           // staging row in 8-row group
  const int sk = (((l & 7) ^ (l >> 3)) << 3);      // pre-swizzled global k offset

  const float4 zf4 = make_float4(0.f, 0.f, 0.f, 0.f);

  u32 pv[2][K];                                    // packed top-8 per owned q-row
#pragma unroll
  for (int n = 0; n < 2; ++n)
#pragma unroll
    for (int j = 0; j < K; ++j) pv[n][j] = PSENT;
  float tminf[2] = {-3.0e38f, -3.0e38f};

  for (int ct = 0; ct < NCT; ++ct) {
    const int cb = ct * BN;                        // col-in-slice base
    f32x16 acc[2][2];
#pragma unroll
    for (int m = 0; m < 2; ++m)
#pragma unroll
      for (int n = 0; n < 2; ++n)
#pragma unroll
        for (int r = 0; r < 16; ++r) acc[m][n][r] = 0.f;

    for (int kk = 0; kk < D / BK; ++kk) {
      __syncthreads();                             // staging area free
      // fused zero-fill of probs tail (drained by the next barrier anyway)
      {
        size_t g = ((size_t)bid * NIT + (ct * 16 + kk)) * 256 + tid;
        if (g < NZ4) zout[g] = zf4;
      }
      const int kbase = kk * BK;
#pragma unroll
      for (int c = 0; c < 4; ++c) {                // queries -> a_sh
        int r = wid * 32 + c * 8 + sr;
        const u16* gs = qn + (size_t)(rbase + r) * D + kbase + sk;
        __builtin_amdgcn_global_load_lds((const __attribute__((address_space(1))) void*)gs,
            (__attribute__((address_space(3))) void*)(a_sh + wid * 2048 + c * 512), 16, 0, 0);
      }
#pragma unroll
      for (int c = 0; c < 4; ++c) {                // vocab -> b_sh
        int r = wid * 32 + c * 8 + sr;
        const u16* gs = vn + (size_t)(slice * CPS + cb + r) * D + kbase + sk;
        __builtin_amdgcn_global_load_lds((const __attribute__((address_space(1))) void*)gs,
            (__attribute__((address_space(3))) void*)(b_sh + wid * 2048 + c * 512), 16, 0, 0);
      }
      __syncthreads();                             // drains vmcnt -> LDS ready
      __builtin_amdgcn_s_setprio(1);
#pragma unroll
      for (int t = 0; t < 4; ++t) {                // 4 k-steps of 16
        const int ch = t * 2 + h;                  // 16B chunk index within row
        bf16x8 vf[2], qf[2];
#pragma unroll
        for (int m = 0; m < 2; ++m) {
          int row = wr * 64 + m * 32 + lid;
          vf[m] = *reinterpret_cast<const bf16x8*>(b_sh + row * BK + ((ch ^ (row & 7)) << 3));
        }
#pragma unroll
        for (int n = 0; n < 2; ++n) {
          int row = wc * 64 + n * 32 + lid;
          qf[n] = *reinterpret_cast<const bf16x8*>(a_sh + row * BK + ((ch ^ (row & 7)) << 3));
        }
#pragma unroll
        for (int m = 0; m < 2; ++m)
#pragma unroll
          for (int n = 0; n < 2; ++n)
            acc[m][n] = __builtin_amdgcn_mfma_f32_32x32x16_bf16(vf[m], qf[n], acc[m][n], 0, 0, 0);
      }
      __builtin_amdgcn_s_setprio(0);
    }

    // ---- in-register scan: per n (owned q-row), 2x16 values with col ids from reg
#pragma unroll
    for (int n = 0; n < 2; ++n) {
#pragma unroll
      for (int m = 0; m < 2; ++m) {
        f32x16 a = acc[m][n];
        float x01 = fmaxf(a[0], a[1]),   x23 = fmaxf(a[2], a[3]);
        float x45 = fmaxf(a[4], a[5]),   x67 = fmaxf(a[6], a[7]);
        float x89 = fmaxf(a[8], a[9]),   xab = fmaxf(a[10], a[11]);
        float xcd = fmaxf(a[12], a[13]), xef = fmaxf(a[14], a[15]);
        float mx = fmaxf(fmaxf(fmaxf(x01, x23), fmaxf(x45, x67)),
                         fmaxf(fmaxf(x89, xab), fmaxf(xcd, xef)));
        if (mx > tminf[n]) {
          const int cidb = cb + wr * 64 + m * 32 + 4 * h;
#pragma unroll
          for (int r = 0; r < 16; ++r) {
            float v = a[r];
            if (v > tminf[n]) {
              int cid = cidb + (r & 3) + 8 * (r >> 2);
              u32 p = (flipbits(v) & 0xFFFFFC00u) | (u32)(1023 - cid);
              insert8(pv[n], p);
            }
          }
          tminf[n] = unpackval(pv[n][K - 1]);
        }
      }
    }
  }

  // ---- merge 4 contributors (wr x h) per q-row -> per-slice top-8
  __syncthreads();
  u32* marr = (u32*)sh;                            // [128 rows][4 contrib][8] = 16 KB
#pragma unroll
  for (int n = 0; n < 2; ++n)
#pragma unroll
    for (int j = 0; j < K; ++j)
      marr[((wc * 64 + n * 32 + lid) * 4 + (wr * 2 + h)) * K + j] = pv[n][j];
  __syncthreads();
  if (tid < BM) {
    u32 fv[K];
#pragma unroll
    for (int j = 0; j < K; ++j) fv[j] = PSENT;
#pragma unroll
    for (int c4 = 0; c4 < 4; ++c4)
#pragma unroll
      for (int j = 0; j < K; ++j) insert8(fv, marr[(tid * 4 + c4) * K + j]);
#pragma unroll
    for (int j = 0; j < K; ++j)
      cand[(size_t)(rbase + tid) * NCAND + slice * K + j] = fv[j];
  }
}

// ------- approx top-16 merge + exact fp32 rescore + top-8 + softmax (1 wave/row)
__global__ __launch_bounds__(256)
void rescore_kernel(const u32* __restrict__ cand,
                    const float* __restrict__ emb, const float* __restrict__ vocab,
                    const float* __restrict__ invq, const float* __restrict__ invv,
                    float* __restrict__ res_p, int* __restrict__ res_i) {
  const int tid = threadIdx.x, wid = tid >> 6, l = tid & 63;
  const int row = blockIdx.x * 4 + wid;

  float4 q[4];                                     // emb row: lane l holds float4s t*64+l
#pragma unroll
  for (int t = 0; t < 4; ++t)
    q[t] = *(reinterpret_cast<const float4*>(emb + (size_t)row * D) + t * 64 + l);
  float iqr = invq[row];

  u32 pl[CPL]; int li[CPL];                        // packed candidates + global ids
#pragma unroll
  for (int t = 0; t < CPL; ++t) {
    int e = l * CPL + t;
    bool ok = e < NCAND;
    u32 p = ok ? cand[(size_t)row * NCAND + e] : PSENT;
    pl[t] = ok ? p : 0u;
    li[t] = ok ? ((e >> 3) * CPS + 1023 - (int)(p & 1023u)) : 0x7fffffff;
  }

  int cidx[T16];                                   // approx top-16 by iterative extraction
#pragma unroll
  for (int jr = 0; jr < T16; ++jr) {
    u32 bp = pl[0]; int bi = li[0];
#pragma unroll
    for (int t = 1; t < CPL; ++t)
      if (pl[t] > bp || (pl[t] == bp && li[t] < bi)) { bp = pl[t]; bi = li[t]; }
#pragma unroll
    for (int off = 32; off > 0; off >>= 1) {
      u32 op = (u32)__shfl_xor((int)bp, off, 64); int oi = __shfl_xor(bi, off, 64);
      if (op > bp || (op == bp && oi < bi)) { bp = op; bi = oi; }
    }
    cidx[jr] = bi;
#pragma unroll
    for (int t = 0; t < CPL; ++t) if (li[t] == bi) pl[t] = 0u;
  }

  float sv[T16];                                   // exact fp32 cosine for each candidate
#pragma unroll
  for (int jr = 0; jr < T16; ++jr) {
    int ix = cidx[jr];
    const float4* vr = reinterpret_cast<const float4*>(vocab + (size_t)ix * D);
    float s = 0.f;
#pragma unroll
    for (int t = 0; t < 4; ++t) {
      float4 vv = vr[t * 64 + l];
      s += q[t].x * vv.x + q[t].y * vv.y + q[t].z * vv.z + q[t].w * vv.w;
    }
#pragma unroll
    for (int off = 32; off > 0; off >>= 1) s += __shfl_xor(s, off, 64);
    sv[jr] = s * iqr * invv[ix];
  }

  float pvv[K]; int pii[K];                        // exact top-8, idx-asc on ties
#pragma unroll
  for (int r8 = 0; r8 < K; ++r8) {
    float bv = sv[0]; int bi = cidx[0];
#pragma unroll
    for (int jr = 1; jr < T16; ++jr)
      if (sv[jr] > bv || (sv[jr] == bv && cidx[jr] < bi)) { bv = sv[jr]; bi = cidx[jr]; }
    pvv[r8] = bv; pii[r8] = bi;
#pragma unroll
    for (int jr = 0; jr < T16; ++jr) if (cidx[jr] == bi) sv[jr] = -3.0e38f;
  }

  float m = pvv[0], sum = 0.f, e8[K];
#pragma unroll
  for (int j = 0; j < K; ++j) { e8[j] = expf(pvv[j] - m); sum += e8[j]; }
  float isum = 1.f / sum;
  if (l == 0) {
#pragma unroll
    for (int j = 0; j < K; ++j) {
      res_p[row * K + j] = e8[j] * isum;
      res_i[row * K + j] = pii[j];
    }
  }
}

// --------------------------------------------- final scatter into zeroed probs
__global__ void scatter_kernel(const float* __restrict__ res_p, const int* __restrict__ res_i,
                               float* __restrict__ out) {
  int row = blockIdx.x * blockDim.x + threadIdx.x;
#pragma unroll
  for (int j = 0; j < K; ++j) out[(size_t)row * V + res_i[row * K + j]] = res_p[row * K + j];
  out[(size_t)N * V + row] = (float)res_i[row * K];  // token id = exact argmax
}

extern "C" void kernel_launch(void* const* d_in, const int* in_sizes, int n_in,
                              void* d_out, int out_size, void* d_ws, size_t ws_size,
                              hipStream_t stream) {
  const float* emb   = (const float*)d_in[0];
  const float* vocab = (const float*)d_in[1];
  float* out = (float*)d_out;

  // scratch carved out of d_out (probs region; re-zeroed before scatter)
  u16* qn = (u16*)d_out;                                   // 8 MB normalized bf16 Q
  u16* vn = qn + (size_t)N * D;                            // 64 MB normalized bf16 V
  u32* cand = (u32*)((char*)d_out + CAND_OFS);             // 6.4 MB
  float4* ztail = (float4*)((char*)d_out + ZOFS);          // zero-fill target in simtopk

  float* wsf   = (float*)d_ws;
  float* invq  = wsf;                                      // N
  float* invv  = wsf + N;                                  // V
  float* res_p = wsf + N + V;                              // N*K
  int*   res_i = (int*)(wsf + N + V + N * K);              // N*K

  normcvt_kernel<<<N, 256, 0, stream>>>(emb, invq, qn);
  normcvt_kernel<<<V, 256, 0, stream>>>(vocab, invv, vn);
  simtopk_kernel<<<GRID, 256, 0, stream>>>(qn, vn, cand, ztail);
  rescore_kernel<<<N / 4, 256, 0, stream>>>(cand, emb, vocab, invq, invv, res_p, res_i);
  zero_kernel<<<2048, 256, 0, stream>>>((float4*)d_out, (int)(ZOFS / 16));  // scratch region
  scatter_kernel<<<N / 256, 256, 0, stream>>>(res_p, res_i, out);
}

// Round 7
// 535.785 us; speedup vs baseline: 10.4502x; 1.0863x over previous
//
#include <hip/hip_runtime.h>
#include <math.h>

typedef unsigned short u16;
typedef unsigned int u32;
typedef float f32x16 __attribute__((ext_vector_type(16)));
typedef short bf16x8 __attribute__((ext_vector_type(8)));
typedef u16 u16x4 __attribute__((ext_vector_type(4)));

static constexpr int N = 4096;         // B*L
static constexpr int D = 1024;
static constexpr int V = 32000;
static constexpr int K = 8;
static constexpr int BM = 128, BN = 128, BK = 64;
static constexpr int NTILES = V / BN;  // 250 col-tiles of 128
static constexpr int NG = 32;          // col-tile groups (7 or 8 tiles each)
static constexpr int NCAND = NG * K;   // 256 approx candidates per row
static constexpr int T16 = 16;         // rescored candidates per row
static constexpr int CPL = NCAND / 64; // 4 candidates per lane, exact
static constexpr int GRID = NG * (N / BM);   // 1024 = exactly 4 blocks/CU
static constexpr u32 PSENT = 0x00800000u;    // packed(-3.4e38), unsigned-min sentinel

// d_out layout: [qn 8MB | vn 62.5MB | pad | cand @80MiB (4MB) | zero-tail @ZOFS .. N*V*4) [ids]
static constexpr size_t OUT_PROB_BYTES = (size_t)N * V * 4;            // 524,288,000
static constexpr size_t CAND_OFS = 83886080;                           // 80 MiB
static constexpr size_t ZOFS = CAND_OFS + (size_t)N * NCAND * 4;       // 88,080,384 (16B aligned)
static constexpr size_t NZ4 = (OUT_PROB_BYTES - ZOFS) / 16;            // 27,262,976 = 104*1024*256

static_assert(N % BM == 0 && V % BN == 0, "tiling");
static_assert(ZOFS % 16 == 0, "align");
static_assert(NZ4 == (size_t)104 * GRID * 256, "zero quota");          // 104 <= 112 min items/block

__device__ __forceinline__ u16 f2bf(float f) {
  u32 u = __float_as_uint(f);
  return (u16)((u + 0x7fffu + ((u >> 16) & 1u)) >> 16);
}
// monotone f32 -> sortable u32
__device__ __forceinline__ u32 flipbits(float v) {
  u32 u = __float_as_uint(v);
  return u ^ (((u32)((int)u >> 31)) | 0x80000000u);
}
// upper bound of packed slot's value
__device__ __forceinline__ float unpackval(u32 p) {
  u32 s = p | 1023u;
  u32 u = (s & 0x80000000u) ? (s ^ 0x80000000u) : ~s;
  return __uint_as_float(u);
}
// descending-sorted 8-slot insert, unsigned compare
__device__ __forceinline__ void insert8(u32 pv[K], u32 x) {
  if (x <= pv[K - 1]) return;
  bool g[K];
#pragma unroll
  for (int j = 0; j < K; ++j) g[j] = x > pv[j];
#pragma unroll
  for (int j = K - 1; j >= 1; --j)
    pv[j] = g[j - 1] ? pv[j - 1] : (g[j] ? x : pv[j]);
  if (g[0]) pv[0] = x;
}

// ---------------------------------------------------------------- zero (scratch region only)
__global__ void zero_kernel(float4* __restrict__ p, int n4) {
  int i = blockIdx.x * blockDim.x + threadIdx.x;
  int stride = gridDim.x * blockDim.x;
  float4 z = make_float4(0.f, 0.f, 0.f, 0.f);
  for (; i < n4; i += stride) p[i] = z;
}

// ---------------- fused: inverse L2 norm + normalized bf16 copy (one fp32 read)
__global__ void normcvt_kernel(const float* __restrict__ x, float* __restrict__ inv,
                               u16* __restrict__ o) {
  int row = blockIdx.x;
  const float4* xr = reinterpret_cast<const float4*>(x + (size_t)row * D);
  float4 v = xr[threadIdx.x];
  float ss = v.x * v.x + v.y * v.y + v.z * v.z + v.w * v.w;
#pragma unroll
  for (int off = 32; off > 0; off >>= 1) ss += __shfl_down(ss, off, 64);
  __shared__ float wsum[4];
  if ((threadIdx.x & 63) == 0) wsum[threadIdx.x >> 6] = ss;
  __syncthreads();
  __shared__ float s_inv;
  if (threadIdx.x == 0) {
    float t = wsum[0] + wsum[1] + wsum[2] + wsum[3];
    float iv = 1.0f / fmaxf(sqrtf(t), 1e-12f);
    inv[row] = iv;
    s_inv = iv;
  }
  __syncthreads();
  float s = s_inv;
  u16x4 r;
  r[0] = f2bf(v.x * s); r[1] = f2bf(v.y * s); r[2] = f2bf(v.z * s); r[3] = f2bf(v.w * s);
  *reinterpret_cast<u16x4*>(o + (size_t)row * D + threadIdx.x * 4) = r;
}

// ------- bf16 MFMA sims (SWAPPED operands: A=vocab, B=query) + in-register top-8
// Grid = 1024 = exactly 4 blocks/CU (zero dispatch-tail). Block = (rowblock, group);
// group g owns col-tiles [g*250/32, (g+1)*250/32) (7 or 8 tiles). Single 32KB LDS
// buffer, barrier-drain per k-step, fused tail zero-fill, launch_bounds(256,4).
__global__ __launch_bounds__(256, 4)
void simtopk_kernel(const u16* __restrict__ qn, const u16* __restrict__ vn,
                    u32* __restrict__ cand, float4* __restrict__ zout) {
  __shared__ __align__(16) u16 sh[2 * BM * BK];    // 32 KB: {A, B}; aliased as merge buf

  u16* a_sh = sh;                                  // query tile [128][64]
  u16* b_sh = sh + BM * BK;                        // vocab tile [128][64]

  const int tid = threadIdx.x;
  const int bid = blockIdx.x;
  // XCD-aware: XCD x (=bid&7) owns groups 4x..4x+3; rowblock fast-varying.
  const int u = bid >> 3;
  const int rb = u & 31;                           // rowblock
  const int grp = (bid & 7) * 4 + (u >> 5);        // col-tile group
  const int t0 = (grp * NTILES) >> 5;              // first col-tile
  const int t1 = ((grp + 1) * NTILES) >> 5;        // past-last col-tile (t1-t0 = 7 or 8)
  const int rbase = rb * BM;
  const int wid = tid >> 6, l = tid & 63;
  const int wr = wid >> 1, wc = wid & 1;
  const int h = l >> 5, lid = l & 31;
  const int sr = l >> 3;                           // staging row in 8-row group
  const int sk = (((l & 7) ^ (l >> 3)) << 3);      // pre-swizzled global k offset

  const float4 zf4 = make_float4(0.f, 0.f, 0.f, 0.f);

  u32 pv[2][K];                                    // packed top-8 per owned q-row
#pragma unroll
  for (int n = 0; n < 2; ++n)
#pragma unroll
    for (int j = 0; j < K; ++j) pv[n][j] = PSENT;
  float tminf[2] = {-3.0e38f, -3.0e38f};

  for (int ti = t0; ti < t1; ++ti) {
    const int cb = (ti - t0) * BN;                 // local col base (packed cid space)
    f32x16 acc[2][2];
#pragma unroll
    for (int m = 0; m < 2; ++m)
#pragma unroll
      for (int n = 0; n < 2; ++n)
#pragma unroll
        for (int r = 0; r < 16; ++r) acc[m][n][r] = 0.f;

    for (int kk = 0; kk < D / BK; ++kk) {
      __syncthreads();                             // staging area free
      // fused zero-fill of probs tail (drained by the next barrier anyway)
      {
        int it = (ti - t0) * 16 + kk;              // 0..111/127; quota needs it<104
        size_t g = (size_t)it * (GRID * 256) + (size_t)bid * 256 + tid;
        if (g < NZ4) zout[g] = zf4;
      }
      const int kbase = kk * BK;
#pragma unroll
      for (int c = 0; c < 4; ++c) {                // queries -> a_sh
        int r = wid * 32 + c * 8 + sr;
        const u16* gs = qn + (size_t)(rbase + r) * D + kbase + sk;
        __builtin_amdgcn_global_load_lds((const __attribute__((address_space(1))) void*)gs,
            (__attribute__((address_space(3))) void*)(a_sh + wid * 2048 + c * 512), 16, 0, 0);
      }
#pragma unroll
      for (int c = 0; c < 4; ++c) {                // vocab -> b_sh
        int r = wid * 32 + c * 8 + sr;
        const u16* gs = vn + (size_t)(ti * BN + r) * D + kbase + sk;
        __builtin_amdgcn_global_load_lds((const __attribute__((address_space(1))) void*)gs,
            (__attribute__((address_space(3))) void*)(b_sh + wid * 2048 + c * 512), 16, 0, 0);
      }
      __syncthreads();                             // drains vmcnt -> LDS ready
      __builtin_amdgcn_s_setprio(1);
#pragma unroll
      for (int t = 0; t < 4; ++t) {                // 4 k-steps of 16
        const int ch = t * 2 + h;                  // 16B chunk index within row
        bf16x8 vf[2], qf[2];
#pragma unroll
        for (int m = 0; m < 2; ++m) {
          int row = wr * 64 + m * 32 + lid;
          vf[m] = *reinterpret_cast<const bf16x8*>(b_sh + row * BK + ((ch ^ (row & 7)) << 3));
        }
#pragma unroll
        for (int n = 0; n < 2; ++n) {
          int row = wc * 64 + n * 32 + lid;
          qf[n] = *reinterpret_cast<const bf16x8*>(a_sh + row * BK + ((ch ^ (row & 7)) << 3));
        }
#pragma unroll
        for (int m = 0; m < 2; ++m)
#pragma unroll
          for (int n = 0; n < 2; ++n)
            acc[m][n] = __builtin_amdgcn_mfma_f32_32x32x16_bf16(vf[m], qf[n], acc[m][n], 0, 0, 0);
      }
      __builtin_amdgcn_s_setprio(0);
    }

    // ---- in-register scan: per n (owned q-row), 2x16 values with col ids from reg
#pragma unroll
    for (int n = 0; n < 2; ++n) {
#pragma unroll
      for (int m = 0; m < 2; ++m) {
        f32x16 a = acc[m][n];
        float x01 = fmaxf(a[0], a[1]),   x23 = fmaxf(a[2], a[3]);
        float x45 = fmaxf(a[4], a[5]),   x67 = fmaxf(a[6], a[7]);
        float x89 = fmaxf(a[8], a[9]),   xab = fmaxf(a[10], a[11]);
        float xcd = fmaxf(a[12], a[13]), xef = fmaxf(a[14], a[15]);
        float mx = fmaxf(fmaxf(fmaxf(x01, x23), fmaxf(x45, x67)),
                         fmaxf(fmaxf(x89, xab), fmaxf(xcd, xef)));
        if (mx > tminf[n]) {
          const int cidb = cb + wr * 64 + m * 32 + 4 * h;
#pragma unroll
          for (int r = 0; r < 16; ++r) {
            float v = a[r];
            if (v > tminf[n]) {
              int cid = cidb + (r & 3) + 8 * (r >> 2);
              u32 p = (flipbits(v) & 0xFFFFFC00u) | (u32)(1023 - cid);
              insert8(pv[n], p);
            }
          }
          tminf[n] = unpackval(pv[n][K - 1]);
        }
      }
    }
  }

  // ---- merge 4 contributors (wr x h) per q-row -> per-group top-8
  __syncthreads();
  u32* marr = (u32*)sh;                            // [128 rows][4 contrib][8] = 16 KB
#pragma unroll
  for (int n = 0; n < 2; ++n)
#pragma unroll
    for (int j = 0; j < K; ++j)
      marr[((wc * 64 + n * 32 + lid) * 4 + (wr * 2 + h)) * K + j] = pv[n][j];
  __syncthreads();
  if (tid < BM) {
    u32 fv[K];
#pragma unroll
    for (int j = 0; j < K; ++j) fv[j] = PSENT;
#pragma unroll
    for (int c4 = 0; c4 < 4; ++c4)
#pragma unroll
      for (int j = 0; j < K; ++j) insert8(fv, marr[(tid * 4 + c4) * K + j]);
#pragma unroll
    for (int j = 0; j < K; ++j)
      cand[(size_t)(rbase + tid) * NCAND + grp * K + j] = fv[j];
  }
}

// ------- approx top-16 merge + exact fp32 rescore + top-8 + softmax (1 wave/row)
__global__ __launch_bounds__(256)
void rescore_kernel(const u32* __restrict__ cand,
                    const float* __restrict__ emb, const float* __restrict__ vocab,
                    const float* __restrict__ invq, const float* __restrict__ invv,
                    float* __restrict__ res_p, int* __restrict__ res_i) {
  const int tid = threadIdx.x, wid = tid >> 6, l = tid & 63;
  const int row = blockIdx.x * 4 + wid;

  float4 q[4];                                     // emb row: lane l holds float4s t*64+l
#pragma unroll
  for (int t = 0; t < 4; ++t)
    q[t] = *(reinterpret_cast<const float4*>(emb + (size_t)row * D) + t * 64 + l);
  float iqr = invq[row];

  u32 pl[CPL]; int li[CPL];                        // packed candidates + global ids (no masking: 64*4==256)
#pragma unroll
  for (int t = 0; t < CPL; ++t) {
    int e = l * CPL + t;
    u32 p = cand[(size_t)row * NCAND + e];
    int grp = e >> 3;
    int tile0 = (grp * NTILES) >> 5;               // group's first col-tile
    pl[t] = p;
    li[t] = tile0 * BN + 1023 - (int)(p & 1023u);
  }

  int cidx[T16];                                   // approx top-16 by iterative extraction
#pragma unroll
  for (int jr = 0; jr < T16; ++jr) {
    u32 bp = pl[0]; int bi = li[0];
#pragma unroll
    for (int t = 1; t < CPL; ++t)
      if (pl[t] > bp || (pl[t] == bp && li[t] < bi)) { bp = pl[t]; bi = li[t]; }
#pragma unroll
    for (int off = 32; off > 0; off >>= 1) {
      u32 op = (u32)__shfl_xor((int)bp, off, 64); int oi = __shfl_xor(bi, off, 64);
      if (op > bp || (op == bp && oi < bi)) { bp = op; bi = oi; }
    }
    cidx[jr] = bi;
#pragma unroll
    for (int t = 0; t < CPL; ++t) if (li[t] == bi) pl[t] = 0u;
  }

  float sv[T16];                                   // exact fp32 cosine for each candidate
#pragma unroll
  for (int jr = 0; jr < T16; ++jr) {
    int ix = cidx[jr];
    const float4* vr = reinterpret_cast<const float4*>(vocab + (size_t)ix * D);
    float s = 0.f;
#pragma unroll
    for (int t = 0; t < 4; ++t) {
      float4 vv = vr[t * 64 + l];
      s += q[t].x * vv.x + q[t].y * vv.y + q[t].z * vv.z + q[t].w * vv.w;
    }
#pragma unroll
    for (int off = 32; off > 0; off >>= 1) s += __shfl_xor(s, off, 64);
    sv[jr] = s * iqr * invv[ix];
  }

  float pvv[K]; int pii[K];                        // exact top-8, idx-asc on ties
#pragma unroll
  for (int r8 = 0; r8 < K; ++r8) {
    float bv = sv[0]; int bi = cidx[0];
#pragma unroll
    for (int jr = 1; jr < T16; ++jr)
      if (sv[jr] > bv || (sv[jr] == bv && cidx[jr] < bi)) { bv = sv[jr]; bi = cidx[jr]; }
    pvv[r8] = bv; pii[r8] = bi;
#pragma unroll
    for (int jr = 0; jr < T16; ++jr) if (cidx[jr] == bi) sv[jr] = -3.0e38f;
  }

  float m = pvv[0], sum = 0.f, e8[K];
#pragma unroll
  for (int j = 0; j < K; ++j) { e8[j] = expf(pvv[j] - m); sum += e8[j]; }
  float isum = 1.f / sum;
  if (l == 0) {
#pragma unroll
    for (int j = 0; j < K; ++j) {
      res_p[row * K + j] = e8[j] * isum;
      res_i[row * K + j] = pii[j];
    }
  }
}

// --------------------------------------------- final scatter into zeroed probs
__global__ void scatter_kernel(const float* __restrict__ res_p, const int* __restrict__ res_i,
                               float* __restrict__ out) {
  int row = blockIdx.x * blockDim.x + threadIdx.x;
#pragma unroll
  for (int j = 0; j < K; ++j) out[(size_t)row * V + res_i[row * K + j]] = res_p[row * K + j];
  out[(size_t)N * V + row] = (float)res_i[row * K];  // token id = exact argmax
}

extern "C" void kernel_launch(void* const* d_in, const int* in_sizes, int n_in,
                              void* d_out, int out_size, void* d_ws, size_t ws_size,
                              hipStream_t stream) {
  const float* emb   = (const float*)d_in[0];
  const float* vocab = (const float*)d_in[1];
  float* out = (float*)d_out;

  // scratch carved out of d_out (probs region; re-zeroed before scatter)
  u16* qn = (u16*)d_out;                                   // 8 MB normalized bf16 Q
  u16* vn = qn + (size_t)N * D;                            // 64 MB normalized bf16 V
  u32* cand = (u32*)((char*)d_out + CAND_OFS);             // 4 MB
  float4* ztail = (float4*)((char*)d_out + ZOFS);          // zero-fill target in simtopk

  float* wsf   = (float*)d_ws;
  float* invq  = wsf;                                      // N
  float* invv  = wsf + N;                                  // V
  float* res_p = wsf + N + V;                              // N*K
  int*   res_i = (int*)(wsf + N + V + N * K);              // N*K

  normcvt_kernel<<<N, 256, 0, stream>>>(emb, invq, qn);
  normcvt_kernel<<<V, 256, 0, stream>>>(vocab, invv, vn);
  simtopk_kernel<<<GRID, 256, 0, stream>>>(qn, vn, cand, ztail);
  rescore_kernel<<<N / 4, 256, 0, stream>>>(cand, emb, vocab, invq, invv, res_p, res_i);
  zero_kernel<<<2048, 256, 0, stream>>>((float4*)d_out, (int)(ZOFS / 16));  // scratch region
  scatter_kernel<<<N / 256, 256, 0, stream>>>(res_p, res_i, out);
}